// Round 10
// baseline (138.935 us; speedup 1.0000x reference)
//
#include <hip/hip_runtime.h>
#include <hip/hip_bf16.h>

// b=1, c=256, h=w=64 -> n=4096 pixels, 4 heads, hd=64, 32 groups x 8 ch.
// scale = hd^-0.5 * log2(e) = 0.18033688, folded into Wq (K0) and bq (K1
// epilogue) so attention softmax uses native v_exp_f32 (exp2) directly.
#define NPIX 4096
#define CCH  256
#define HD   64
#define GSIZE 32768   // 8 ch * 4096 pix per group

#define QSCALE 0.18033688f   // 0.125 * log2(e); softmax in base-2 domain

typedef __bf16 bf16x8 __attribute__((ext_vector_type(8)));
typedef __bf16 bf16x4 __attribute__((ext_vector_type(4)));
typedef __bf16 bf16x2 __attribute__((ext_vector_type(2)));
typedef float  f32x4  __attribute__((ext_vector_type(4)));
typedef unsigned int uint32x4 __attribute__((ext_vector_type(4)));

#define XPITCH 264   // X/F panel pitch (bf16) for K1/K3

#if __has_builtin(__builtin_amdgcn_exp2f)
#define EXP2(x) __builtin_amdgcn_exp2f(x)
#else
#define EXP2(x) __expf((x) * 0.6931471805599453f)
#endif

// MFMA 16x16x32_bf16 layouts (verified m89/m91):
//   A[m=lane&15][k=quad*8+j]; B[k=quad*8+j][n=lane&15]; C: row=quad*4+reg, col=lane&15

__device__ __forceinline__ unsigned pack_bf16x2(float lo, float hi)
{
    bf16x2 v;
    v[0] = (__bf16)lo;
    v[1] = (__bf16)hi;
    return __builtin_bit_cast(unsigned, v);
}

// direct global->LDS DMA, 16B per lane; LDS dest = wave-uniform base + lane*16
__device__ __forceinline__ void gload_lds16(const void* g, void* l)
{
    __builtin_amdgcn_global_load_lds(
        (const __attribute__((address_space(1))) void*)g,
        (__attribute__((address_space(3))) void*)l, 16, 0, 0);
}

// ---------------------------------------------------------------------------
// K0: blocks 0..255: per-(group,1/8th) partial sums -> psum/pssq[256].
//     blocks 256..319: weight fp32->bf16 convert (Wq scaled by QSCALE).
// ---------------------------------------------------------------------------
__global__ __launch_bounds__(256) void stats_wconv(
    const float* __restrict__ X,
    const float* __restrict__ Wq, const float* __restrict__ Wk,
    const float* __restrict__ Wv, const float* __restrict__ Wp,
    float* __restrict__ psum, float* __restrict__ pssq, __bf16* __restrict__ Wb)
{
    const int bid = blockIdx.x, t = threadIdx.x;
    if (bid < 256) {
        const float* base = X + bid * 4096;   // (g = bid>>3, seg = bid&7)
        float sum = 0.f, ssq = 0.f;
        #pragma unroll
        for (int k = 0; k < 4; ++k) {
            float4 v = *(const float4*)(base + t * 4 + k * 1024);
            sum += v.x + v.y + v.z + v.w;
            ssq += v.x * v.x + v.y * v.y + v.z * v.z + v.w * v.w;
        }
        #pragma unroll
        for (int off = 1; off < 64; off <<= 1) {
            sum += __shfl_xor(sum, off);
            ssq += __shfl_xor(ssq, off);
        }
        __shared__ float red[2][4];
        const int wv = t >> 6;
        if ((t & 63) == 0) { red[0][wv] = sum; red[1][wv] = ssq; }
        __syncthreads();
        if (t == 0) {
            psum[bid] = red[0][0] + red[0][1] + red[0][2] + red[0][3];
            pssq[bid] = red[1][0] + red[1][1] + red[1][2] + red[1][3];
        }
    } else {
        const int j0 = (bid - 256) * 4096 + t * 16;
        const int m  = j0 >> 16;
        const float* W = (m == 0) ? Wq : (m == 1) ? Wk : (m == 2) ? Wv : Wp;
        const float sc = (m == 0) ? QSCALE : 1.f;
        const int off = j0 & 65535;
        #pragma unroll
        for (int k = 0; k < 4; ++k) {
            float4 v = *(const float4*)(W + off + k * 4);
            bf16x4 o;
            o[0] = (__bf16)(v.x * sc); o[1] = (__bf16)(v.y * sc);
            o[2] = (__bf16)(v.z * sc); o[3] = (__bf16)(v.w * sc);
            *(bf16x4*)(Wb + m * 65536 + off + k * 4) = o;
        }
    }
}

// ---------------------------------------------------------------------------
// K1: fused GroupNorm-apply + QKV MFMA GEMM. grid (64 pixblk, 6: z*2+och).
// (unchanged; qs = QSCALE)
// ---------------------------------------------------------------------------
__global__ __launch_bounds__(256) void gn_qkv(
    const float* __restrict__ X, const float* __restrict__ gamma,
    const float* __restrict__ beta,
    const float* __restrict__ psum, const float* __restrict__ pssq,
    const __bf16* __restrict__ Wb,
    const float* __restrict__ bq, const float* __restrict__ bk,
    const float* __restrict__ bv,
    __bf16* __restrict__ Qb, __bf16* __restrict__ Kb, __bf16* __restrict__ Vb)
{
    __shared__ __bf16 tile[64 * XPITCH];
    __shared__ float al[256], bl[256];

    const int t = threadIdx.x, lane = t & 63, wave = t >> 6;
    const int l16 = lane & 15, quad = lane >> 4;
    const int p0 = blockIdx.x * 64;
    const int z = blockIdx.y >> 1, och = blockIdx.y & 1;

    {
        const int g = t >> 3;
        float s = 0.f, q = 0.f;
        #pragma unroll
        for (int j = 0; j < 8; ++j) { s += psum[g * 8 + j]; q += pssq[g * 8 + j]; }
        const float mu  = s * (1.f / GSIZE);
        const float var = q * (1.f / GSIZE) - mu * mu;
        const float a = gamma[t] * rsqrtf(var + 1e-6f);
        al[t] = a;
        bl[t] = beta[t] - mu * a;
    }
    __syncthreads();

    #pragma unroll 4
    for (int i = 0; i < 16; ++i) {
        const int c4 = wave * 64 + i * 4;
        f32x4 a4 = *(const f32x4*)(al + c4);
        f32x4 b4 = *(const f32x4*)(bl + c4);
        bf16x4 pk;
        pk[0] = (__bf16)(X[(c4 + 0) * NPIX + p0 + lane] * a4[0] + b4[0]);
        pk[1] = (__bf16)(X[(c4 + 1) * NPIX + p0 + lane] * a4[1] + b4[1]);
        pk[2] = (__bf16)(X[(c4 + 2) * NPIX + p0 + lane] * a4[2] + b4[2]);
        pk[3] = (__bf16)(X[(c4 + 3) * NPIX + p0 + lane] * a4[3] + b4[3]);
        *(bf16x4*)(tile + lane * XPITCH + c4) = pk;
    }
    __syncthreads();

    const int pw = wave * 16;
    bf16x8 xf[8];
    #pragma unroll
    for (int kc = 0; kc < 8; ++kc)
        xf[kc] = *(const bf16x8*)(tile + (pw + l16) * XPITCH + kc * 32 + quad * 8);

    const __bf16* Wz = Wb + z * 65536;
    const float* bias = (z == 0) ? bq : (z == 1) ? bk : bv;

    if (z < 2) {
        const float qs = (z == 0) ? QSCALE : 1.f;
        __bf16* dst = (z == 0) ? Qb : Kb;
        #pragma unroll
        for (int grp = 0; grp < 2; ++grp) {
            f32x4 acc[4] = {};
            #pragma unroll
            for (int kc = 0; kc < 8; ++kc) {
                #pragma unroll
                for (int u = 0; u < 4; ++u) {
                    bf16x8 wf = *(const bf16x8*)(Wz + (och * 128 + (grp * 4 + u) * 16 + l16) * CCH + kc * 32 + quad * 8);
                    acc[u] = __builtin_amdgcn_mfma_f32_16x16x32_bf16(wf, xf[kc], acc[u], 0, 0, 0);
                }
            }
            #pragma unroll
            for (int u = 0; u < 4; ++u) {
                const int ot = och * 8 + grp * 4 + u;
                f32x4 bz = *(const f32x4*)(bias + och * 128 + (grp * 4 + u) * 16 + quad * 4);
                bf16x4 o;
                o[0] = (__bf16)(acc[u][0] + bz[0] * qs);
                o[1] = (__bf16)(acc[u][1] + bz[1] * qs);
                o[2] = (__bf16)(acc[u][2] + bz[2] * qs);
                o[3] = (__bf16)(acc[u][3] + bz[3] * qs);
                const int head = ot >> 2, dloc = (ot & 3) * 16 + quad * 4;
                *(bf16x4*)(dst + head * (NPIX * HD) + (p0 + pw + l16) * HD + dloc) = o;
            }
        }
    } else {
        #pragma unroll
        for (int grp = 0; grp < 2; ++grp) {
            f32x4 acc[4] = {};
            #pragma unroll
            for (int kc = 0; kc < 8; ++kc) {
                #pragma unroll
                for (int u = 0; u < 4; ++u) {
                    bf16x8 wf = *(const bf16x8*)(Wz + (och * 128 + (grp * 4 + u) * 16 + l16) * CCH + kc * 32 + quad * 8);
                    acc[u] = __builtin_amdgcn_mfma_f32_16x16x32_bf16(xf[kc], wf, acc[u], 0, 0, 0);
                }
            }
            #pragma unroll
            for (int u = 0; u < 4; ++u) {
                const int oc = och * 128 + (grp * 4 + u) * 16 + l16;
                const float bz = bias[oc];
                bf16x4 o;
                o[0] = (__bf16)(acc[u][0] + bz); o[1] = (__bf16)(acc[u][1] + bz);
                o[2] = (__bf16)(acc[u][2] + bz); o[3] = (__bf16)(acc[u][3] + bz);
                *(bf16x4*)(Vb + oc * NPIX + p0 + pw + quad * 4) = o;
            }
        }
    }
}

// ---------------------------------------------------------------------------
// K2 (R18): R17's allocator-proof DMA-pipelined attention, key-split across
// 2 co-resident blocks/CU. R17 proved the DMA+counted-vmcnt pipeline (attn
// 39->33 us) but ~50% of each tile-period is still barrier/vmcnt/dep stalls
// at 1 block/CU. The R10/R11 "occupancy null" was allocator-contaminated
// (VGPR 80-116 = dissolved prefetch); with DMA staging the pipeline is
// schedule-proof, so a 2nd block can dovetail: its waves issue MFMA while
// ours sit at vmcnt/s_barrier. Assembly from green pieces only:
//   - R17 DMA body verbatim, loop bounds kt0..kt0+16 (16 key-tiles)
//   - R11 grid decode + fp32 (Op,Lp) partial epilogue (green R3)
//   - R13 fused-merge gemm_proj (green R5)
// LDS 70656 x 2 = 141KB < 160KB -> 2 blocks/CU. Pair (bid, bid+256) shares
// head+key-half -> same 512KB L2 set.
// ---------------------------------------------------------------------------
#define OFFK0 0
#define OFFK1 16384
#define OFFV0 32768
#define OFFV1 49152
#define SMEMSZ 70656   // max(64K buffers, 69632 co + 1024 cl) via overlay

__global__ __launch_bounds__(256, 2) void attn_partial(
    const __bf16* __restrict__ Qb, const __bf16* __restrict__ Kb,
    const __bf16* __restrict__ Vb, float* __restrict__ Op,
    float* __restrict__ Lp)
{
    __shared__ __align__(16) char smem[SMEMSZ];

    const int t = threadIdx.x, lane = t & 63, wave = t >> 6;
    const int l16 = lane & 15, quad = lane >> 4;

    const int bid  = blockIdx.x;
    const int head = (bid & 7) >> 1;                    // bits 1-2: head (XCD pin)
    const int half = (bid >> 3) & 1;                    // bit 3: key half
    const int qt   = ((bid >> 4) << 1) | (bid & 1);     // 0..63
    const int p0   = qt * 64;
    const int kt0  = half * 16;                         // this block's 16 key-tiles

    const __bf16* Qh = Qb + head * (NPIX * HD);

    // Q B-frags for 64 shared rows: B[k=d][n=row16]
    bf16x8 qf[4][2];
    #pragma unroll
    for (int rt = 0; rt < 4; ++rt) {
        const __bf16* qp = Qh + (p0 + rt * 16 + l16) * HD + quad * 8;
        qf[rt][0] = *(const bf16x8*)(qp);
        qf[rt][1] = *(const bf16x8*)(qp + 32);
    }

    bf16x8 ones;
    #pragma unroll
    for (int j = 0; j < 8; ++j) ones[j] = (__bf16)1.0f;

    f32x4 l_acc[4] = {};
    f32x4 o_acc[4][4] = {};   // [dt][rt]

    // ---- staging (8 DMA instr / wave / tile) ----
    const int lr3 = lane >> 3, lc3 = lane & 7;     // K: row-in-chunk, col-chunk
    const int lr4 = lane >> 4, lc4 = lane & 15;    // V: row-in-chunk, col-chunk
    // K: LDS[row][x] = K[row][x ^ ((row&7)<<4)]; row&7 == lr3 here
    const int kcol = ((lc3 ^ lr3) << 4);
    const char* Kg = (const char*)(Kb + (head * NPIX) * HD);
    const char* Vg = (const char*)(Vb + (head * HD) * NPIX);

    auto stageK = [&](int it, int b) {
        char* dst = smem + (b ? OFFK1 : OFFK0) + wave * 4096;  // wave's 32 rows
        const char* src = Kg + (it * 128 + wave * 32) * 128;   // 128 B / K-row
        #pragma unroll
        for (int i = 0; i < 4; ++i)
            gload_lds16(src + (i * 8 + lr3) * 128 + kcol, dst + i * 1024);
    };
    auto stageV = [&](int it, int b) {
        char* dst = smem + (b ? OFFV1 : OFFV0) + wave * 4096;  // wave's 16 d-rows
        const char* src = Vg + (wave * 16) * (NPIX * 2) + it * 256;  // 256 B/tile-row
        #pragma unroll
        for (int i = 0; i < 4; ++i) {
            const int d  = i * 4 + lr4;                 // d-row within wave's 16
            const int sw = (((wave * 16 + d) & 7) << 4);
            gload_lds16(src + d * (NPIX * 2) + ((lc4 << 4) ^ sw), dst + i * 1024);
        }
    };

    // S^T = K Q^T : C(key_local = kt*16+quad*4+r, row = rt*16+l16)
    auto qk = [&](bf16x8 k0, bf16x8 k1, bf16x8 k2, bf16x8 k3,
                  f32x4 (&s0)[4], f32x4 (&s1)[4]) {
        #pragma unroll
        for (int rt = 0; rt < 4; ++rt) {
            s0[rt] = f32x4{0.f, 0.f, 0.f, 0.f};
            s1[rt] = f32x4{0.f, 0.f, 0.f, 0.f};
            s0[rt] = __builtin_amdgcn_mfma_f32_16x16x32_bf16(k0, qf[rt][0], s0[rt], 0, 0, 0);
            s0[rt] = __builtin_amdgcn_mfma_f32_16x16x32_bf16(k1, qf[rt][1], s0[rt], 0, 0, 0);
            s1[rt] = __builtin_amdgcn_mfma_f32_16x16x32_bf16(k2, qf[rt][0], s1[rt], 0, 0, 0);
            s1[rt] = __builtin_amdgcn_mfma_f32_16x16x32_bf16(k3, qf[rt][1], s1[rt], 0, 0, 0);
        }
    };

    auto pvx = [&](const f32x4 (&s0)[4], const f32x4 (&s1)[4],
                   bf16x8 v0, bf16x8 v1, bf16x8 v2, bf16x8 v3) {
        #pragma unroll
        for (int rt = 0; rt < 4; ++rt) {
            unsigned a0 = pack_bf16x2(EXP2(s0[rt][0]), EXP2(s0[rt][1]));
            unsigned a1 = pack_bf16x2(EXP2(s0[rt][2]), EXP2(s0[rt][3]));
            unsigned b0 = pack_bf16x2(EXP2(s1[rt][0]), EXP2(s1[rt][1]));
            unsigned b1 = pack_bf16x2(EXP2(s1[rt][2]), EXP2(s1[rt][3]));
            // swap32 then swap16: (a0,b0) -> (w0,w2); (a1,b1) -> (w1,w3)
            asm("v_permlane32_swap_b32 %0, %1" : "+v"(a0), "+v"(b0));
            asm("v_permlane32_swap_b32 %0, %1" : "+v"(a1), "+v"(b1));
            asm("v_permlane16_swap_b32 %0, %1" : "+v"(a0), "+v"(b0));
            asm("v_permlane16_swap_b32 %0, %1" : "+v"(a1), "+v"(b1));
            uint32x4 w;
            w[0] = a0; w[1] = a1; w[2] = b0; w[3] = b1;
            const bf16x8 bp = __builtin_bit_cast(bf16x8, w);  // B[k=key32][n=row]
            l_acc[rt] = __builtin_amdgcn_mfma_f32_16x16x32_bf16(ones, bp, l_acc[rt], 0, 0, 0);
            o_acc[0][rt] = __builtin_amdgcn_mfma_f32_16x16x32_bf16(v0, bp, o_acc[0][rt], 0, 0, 0);
            o_acc[1][rt] = __builtin_amdgcn_mfma_f32_16x16x32_bf16(v1, bp, o_acc[1][rt], 0, 0, 0);
            o_acc[2][rt] = __builtin_amdgcn_mfma_f32_16x16x32_bf16(v2, bp, o_acc[2][rt], 0, 0, 0);
            o_acc[3][rt] = __builtin_amdgcn_mfma_f32_16x16x32_bf16(v3, bp, o_acc[3][rt], 0, 0, 0);
        }
    };

    // prologue: tiles kt0, kt0+1 in flight (16 DMAs)
    stageK(kt0, 0); stageV(kt0, 0);
    stageK(kt0 + 1, 1); stageV(kt0 + 1, 1);

    const int ksw = ((l16 & 7) << 4);

    #pragma unroll 1
    for (int it = kt0; it < kt0 + 16; ++it) {
        const int b = it & 1;
        if (it == kt0 + 15) asm volatile("s_waitcnt vmcnt(0)" ::: "memory");
        else                asm volatile("s_waitcnt vmcnt(8)" ::: "memory");
        __builtin_amdgcn_s_barrier();            // all waves' tile-it staged
        __builtin_amdgcn_sched_barrier(0);

        const char* bk = smem + (b ? OFFK1 : OFFK0);
        const char* bv = smem + (b ? OFFV1 : OFFV0);

        // K frags (swizzled read; wave's own 32 rows)
        const int kr0 = (wave * 32 + l16) * 128;
        bf16x8 k0 = *(const bf16x8*)(bk + kr0 + ((quad * 16) ^ ksw));
        bf16x8 k1 = *(const bf16x8*)(bk + kr0 + ((64 + quad * 16) ^ ksw));
        bf16x8 k2 = *(const bf16x8*)(bk + kr0 + 2048 + ((quad * 16) ^ ksw));
        bf16x8 k3 = *(const bf16x8*)(bk + kr0 + 2048 + ((64 + quad * 16) ^ ksw));
        // V frags (swizzled read; all 64 d-rows, wave's 64B key slice)
        const int vcol = (wave * 64 + quad * 16) ^ ksw;
        bf16x8 v0 = *(const bf16x8*)(bv + (l16) * 256 + vcol);
        bf16x8 v1 = *(const bf16x8*)(bv + (16 + l16) * 256 + vcol);
        bf16x8 v2 = *(const bf16x8*)(bv + (32 + l16) * 256 + vcol);
        bf16x8 v3 = *(const bf16x8*)(bv + (48 + l16) * 256 + vcol);

        f32x4 s0[4], s1[4];
        qk(k0, k1, k2, k3, s0, s1);
        pvx(s0, s1, v0, v1, v2, v3);

        __builtin_amdgcn_sched_barrier(0);
        __builtin_amdgcn_s_barrier();            // all waves done reading buf
        if (it < kt0 + 14) { stageK(it + 2, b); stageV(it + 2, b); }
    }

    // ---- in-LDS 4-way key merge (overlay), then fp32 partial store (R11) ----
    float* co = (float*)smem;
    float* cl = (float*)(smem + 69632);

    #pragma unroll
    for (int dt = 0; dt < 4; ++dt)
        #pragma unroll
        for (int rt = 0; rt < 4; ++rt)
            *(f32x4*)(co + wave * 4352 + (rt * 16 + l16) * 68 + dt * 16 + quad * 4) = o_acc[dt][rt];
    if (quad == 0) {
        #pragma unroll
        for (int rt = 0; rt < 4; ++rt)
            cl[wave * 64 + rt * 16 + l16] = l_acc[rt][0];
    }
    __syncthreads();

    {
        const int row = t >> 2, dc = (t & 3) * 16;
        f32x4 s[4];
        #pragma unroll
        for (int j = 0; j < 4; ++j) {
            s[j] = f32x4{0.f, 0.f, 0.f, 0.f};
            #pragma unroll
            for (int w = 0; w < 4; ++w)
                s[j] += *(const f32x4*)(co + w * 4352 + row * 68 + dc + j * 4);
        }
        // un-normalized fp32 partial, R11-proven address convention
        float* dsto = Op + half * (NPIX * CCH) + (p0 + row) * CCH + head * HD + dc;
        #pragma unroll
        for (int j = 0; j < 4; ++j)
            *(f32x4*)(dsto + j * 4) = s[j];
        if ((t & 3) == 0) {
            const float l = cl[row] + cl[64 + row] + cl[128 + row] + cl[192 + row];
            Lp[half * 16384 + head * 4096 + p0 + row] = l;
        }
    }
}

// ---------------------------------------------------------------------------
// K3 (R13-proven): proj GEMM with fused key-half merge in the staging loop.
// Reads the two fp32 partials + Lp, normalizes (P = idx>>8, head =
// (idx>>6)&3 decode), packs bf16 into LDS. GEMM body unchanged.
// ---------------------------------------------------------------------------
__global__ __launch_bounds__(256) void gemm_proj(
    const float* __restrict__ Op, const float* __restrict__ Lp,
    const __bf16* __restrict__ Wpb,
    const float* __restrict__ bias, const float* __restrict__ X,
    float* __restrict__ Out)
{
    __shared__ __bf16 Bs[32 * XPITCH];

    const int t = threadIdx.x, lane = t & 63, wave = t >> 6;
    const int l16 = lane & 15, quad = lane >> 4;
    const int p0  = blockIdx.x * 32;
    const int och = blockIdx.y;

    #pragma unroll
    for (int pg = 0; pg < 4; ++pg) {
        const int col  = p0 + pg * 8;
        const int gidx = t * NPIX + col;          // linear idx in F-space
        const int P    = gidx >> 8;               // q-row (R11-proven decode)
        const int hd8  = (gidx >> 6) & 3;         // head, constant across j
        const float l  = Lp[hd8 * 4096 + P] + Lp[16384 + hd8 * 4096 + P];
        const float inv = 1.f / l;
        f32x4 a0 = *(const f32x4*)(Op + gidx);
        f32x4 a1 = *(const f32x4*)(Op + gidx + 4);
        f32x4 b0 = *(const f32x4*)(Op + NPIX * CCH + gidx);
        f32x4 b1 = *(const f32x4*)(Op + NPIX * CCH + gidx + 4);
        #pragma unroll
        for (int j = 0; j < 4; ++j) {
            Bs[(pg * 8 + j) * XPITCH + t]       = (__bf16)((a0[j] + b0[j]) * inv);
            Bs[(pg * 8 + j + 4) * XPITCH + t]   = (__bf16)((a1[j] + b1[j]) * inv);
        }
    }
    __syncthreads();

    const int pixset = wave & 1, ocset = wave >> 1;
    bf16x8 af[8];
    #pragma unroll
    for (int kc = 0; kc < 8; ++kc)
        af[kc] = *(const bf16x8*)(Bs + (pixset * 16 + l16) * XPITCH + kc * 32 + quad * 8);

    #pragma unroll
    for (int u = 0; u < 4; ++u) {
        f32x4 acc = {};
        const int oc_t = och * 128 + ocset * 64 + u * 16;
        #pragma unroll
        for (int kc = 0; kc < 8; ++kc) {
            bf16x8 wf = *(const bf16x8*)(Wpb + (oc_t + l16) * CCH + kc * 32 + quad * 8);
            acc = __builtin_amdgcn_mfma_f32_16x16x32_bf16(af[kc], wf, acc, 0, 0, 0);
        }
        const int oc  = oc_t + l16;
        const int pix = p0 + pixset * 16 + quad * 4;
        const float bz = bias[oc];
        f32x4 r4 = *(const f32x4*)(X + oc * NPIX + pix);
        f32x4 y;
        y[0] = acc[0] + bz + r4[0];
        y[1] = acc[1] + bz + r4[1];
        y[2] = acc[2] + bz + r4[2];
        y[3] = acc[3] + bz + r4[3];
        *(f32x4*)(Out + oc * NPIX + pix) = y;
    }
}

// ---------------------------------------------------------------------------
extern "C" void kernel_launch(void* const* d_in, const int* in_sizes, int n_in,
                              void* d_out, int out_size, void* d_ws, size_t ws_size,
                              hipStream_t stream)
{
    const float* x     = (const float*)d_in[0];
    const float* gamma = (const float*)d_in[1];
    const float* beta  = (const float*)d_in[2];
    const float* Wq    = (const float*)d_in[3];
    const float* bq    = (const float*)d_in[4];
    const float* Wk    = (const float*)d_in[5];
    const float* bk    = (const float*)d_in[6];
    const float* Wv    = (const float*)d_in[7];
    const float* bv    = (const float*)d_in[8];
    const float* Wp    = (const float*)d_in[9];
    const float* bp    = (const float*)d_in[10];
    float* out = (float*)d_out;

    char* ws = (char*)d_ws;
    float*  psum = (float*)(ws);                // 1KB stats partial sums
    float*  pssq = (float*)(ws + 1024);         // 1KB
    __bf16* Wb   = (__bf16*)(ws + 65536);       // 512KB bf16 4x[256][256]
    __bf16* Qb   = (__bf16*)(ws + (1 << 20));   // 2MB bf16 [head][pix][64]
    __bf16* Kb   = (__bf16*)(ws + (3 << 20));   // 2MB bf16 [head][pix][64]
    __bf16* Vb   = (__bf16*)(ws + (5 << 20));   // 2MB bf16 [c][pix]
    float*  Op   = (float*)(ws + (16 << 20));   // 8MB f32 2x key-half partials
    float*  Lp   = (float*)(ws + (25 << 20));   // 128KB f32 2x[head][pix] sums

    stats_wconv<<<320, 256, 0, stream>>>(x, Wq, Wk, Wv, Wp, psum, pssq, Wb);

    dim3 gq(64, 6);
    gn_qkv<<<gq, 256, 0, stream>>>(x, gamma, beta, psum, pssq, Wb,
                                   bq, bk, bv, Qb, Kb, Vb);

    attn_partial<<<512, 256, 0, stream>>>(Qb, Kb, Vb, Op, Lp);

    dim3 gp(128, 2);
    gemm_proj<<<gp, 256, 0, stream>>>(Op, Lp, Wb + 3 * 65536, bp, x, out);
}

// Round 11
// 133.087 us; speedup vs baseline: 1.0439x; 1.0439x over previous
//
#include <hip/hip_runtime.h>
#include <hip/hip_bf16.h>

// b=1, c=256, h=w=64 -> n=4096 pixels, 4 heads, hd=64, 32 groups x 8 ch.
// scale = hd^-0.5 * log2(e) = 0.18033688, folded into Wq (K0) and bq (K1
// epilogue) so attention softmax uses native v_exp_f32 (exp2) directly.
#define NPIX 4096
#define CCH  256
#define HD   64
#define GSIZE 32768   // 8 ch * 4096 pix per group

#define QSCALE 0.18033688f   // 0.125 * log2(e); softmax in base-2 domain

typedef __bf16 bf16x8 __attribute__((ext_vector_type(8)));
typedef __bf16 bf16x4 __attribute__((ext_vector_type(4)));
typedef __bf16 bf16x2 __attribute__((ext_vector_type(2)));
typedef float  f32x4  __attribute__((ext_vector_type(4)));
typedef unsigned int uint32x4 __attribute__((ext_vector_type(4)));

#define XPITCH 264   // X/F panel pitch (bf16) for K1/K3

#if __has_builtin(__builtin_amdgcn_exp2f)
#define EXP2(x) __builtin_amdgcn_exp2f(x)
#else
#define EXP2(x) __expf((x) * 0.6931471805599453f)
#endif

// MFMA 16x16x32_bf16 layouts (verified m89/m91):
//   A[m=lane&15][k=quad*8+j]; B[k=quad*8+j][n=lane&15]; C: row=quad*4+reg, col=lane&15

__device__ __forceinline__ unsigned pack_bf16x2(float lo, float hi)
{
    bf16x2 v;
    v[0] = (__bf16)lo;
    v[1] = (__bf16)hi;
    return __builtin_bit_cast(unsigned, v);
}

// direct global->LDS DMA, 16B per lane; LDS dest = wave-uniform base + lane*16
__device__ __forceinline__ void gload_lds16(const void* g, void* l)
{
    __builtin_amdgcn_global_load_lds(
        (const __attribute__((address_space(1))) void*)g,
        (__attribute__((address_space(3))) void*)l, 16, 0, 0);
}

// ---------------------------------------------------------------------------
// K0: blocks 0..255: per-(group,1/8th) partial sums -> psum/pssq[256].
//     blocks 256..319: weight fp32->bf16 convert (Wq scaled by QSCALE).
// ---------------------------------------------------------------------------
__global__ __launch_bounds__(256) void stats_wconv(
    const float* __restrict__ X,
    const float* __restrict__ Wq, const float* __restrict__ Wk,
    const float* __restrict__ Wv, const float* __restrict__ Wp,
    float* __restrict__ psum, float* __restrict__ pssq, __bf16* __restrict__ Wb)
{
    const int bid = blockIdx.x, t = threadIdx.x;
    if (bid < 256) {
        const float* base = X + bid * 4096;   // (g = bid>>3, seg = bid&7)
        float sum = 0.f, ssq = 0.f;
        #pragma unroll
        for (int k = 0; k < 4; ++k) {
            float4 v = *(const float4*)(base + t * 4 + k * 1024);
            sum += v.x + v.y + v.z + v.w;
            ssq += v.x * v.x + v.y * v.y + v.z * v.z + v.w * v.w;
        }
        #pragma unroll
        for (int off = 1; off < 64; off <<= 1) {
            sum += __shfl_xor(sum, off);
            ssq += __shfl_xor(ssq, off);
        }
        __shared__ float red[2][4];
        const int wv = t >> 6;
        if ((t & 63) == 0) { red[0][wv] = sum; red[1][wv] = ssq; }
        __syncthreads();
        if (t == 0) {
            psum[bid] = red[0][0] + red[0][1] + red[0][2] + red[0][3];
            pssq[bid] = red[1][0] + red[1][1] + red[1][2] + red[1][3];
        }
    } else {
        const int j0 = (bid - 256) * 4096 + t * 16;
        const int m  = j0 >> 16;
        const float* W = (m == 0) ? Wq : (m == 1) ? Wk : (m == 2) ? Wv : Wp;
        const float sc = (m == 0) ? QSCALE : 1.f;
        const int off = j0 & 65535;
        #pragma unroll
        for (int k = 0; k < 4; ++k) {
            float4 v = *(const float4*)(W + off + k * 4);
            bf16x4 o;
            o[0] = (__bf16)(v.x * sc); o[1] = (__bf16)(v.y * sc);
            o[2] = (__bf16)(v.z * sc); o[3] = (__bf16)(v.w * sc);
            *(bf16x4*)(Wb + m * 65536 + off + k * 4) = o;
        }
    }
}

// ---------------------------------------------------------------------------
// K1: fused GroupNorm-apply + QKV MFMA GEMM. grid (64 pixblk, 6: z*2+och).
// (unchanged; qs = QSCALE)
// ---------------------------------------------------------------------------
__global__ __launch_bounds__(256) void gn_qkv(
    const float* __restrict__ X, const float* __restrict__ gamma,
    const float* __restrict__ beta,
    const float* __restrict__ psum, const float* __restrict__ pssq,
    const __bf16* __restrict__ Wb,
    const float* __restrict__ bq, const float* __restrict__ bk,
    const float* __restrict__ bv,
    __bf16* __restrict__ Qb, __bf16* __restrict__ Kb, __bf16* __restrict__ Vb)
{
    __shared__ __bf16 tile[64 * XPITCH];
    __shared__ float al[256], bl[256];

    const int t = threadIdx.x, lane = t & 63, wave = t >> 6;
    const int l16 = lane & 15, quad = lane >> 4;
    const int p0 = blockIdx.x * 64;
    const int z = blockIdx.y >> 1, och = blockIdx.y & 1;

    {
        const int g = t >> 3;
        float s = 0.f, q = 0.f;
        #pragma unroll
        for (int j = 0; j < 8; ++j) { s += psum[g * 8 + j]; q += pssq[g * 8 + j]; }
        const float mu  = s * (1.f / GSIZE);
        const float var = q * (1.f / GSIZE) - mu * mu;
        const float a = gamma[t] * rsqrtf(var + 1e-6f);
        al[t] = a;
        bl[t] = beta[t] - mu * a;
    }
    __syncthreads();

    #pragma unroll 4
    for (int i = 0; i < 16; ++i) {
        const int c4 = wave * 64 + i * 4;
        f32x4 a4 = *(const f32x4*)(al + c4);
        f32x4 b4 = *(const f32x4*)(bl + c4);
        bf16x4 pk;
        pk[0] = (__bf16)(X[(c4 + 0) * NPIX + p0 + lane] * a4[0] + b4[0]);
        pk[1] = (__bf16)(X[(c4 + 1) * NPIX + p0 + lane] * a4[1] + b4[1]);
        pk[2] = (__bf16)(X[(c4 + 2) * NPIX + p0 + lane] * a4[2] + b4[2]);
        pk[3] = (__bf16)(X[(c4 + 3) * NPIX + p0 + lane] * a4[3] + b4[3]);
        *(bf16x4*)(tile + lane * XPITCH + c4) = pk;
    }
    __syncthreads();

    const int pw = wave * 16;
    bf16x8 xf[8];
    #pragma unroll
    for (int kc = 0; kc < 8; ++kc)
        xf[kc] = *(const bf16x8*)(tile + (pw + l16) * XPITCH + kc * 32 + quad * 8);

    const __bf16* Wz = Wb + z * 65536;
    const float* bias = (z == 0) ? bq : (z == 1) ? bk : bv;

    if (z < 2) {
        const float qs = (z == 0) ? QSCALE : 1.f;
        __bf16* dst = (z == 0) ? Qb : Kb;
        #pragma unroll
        for (int grp = 0; grp < 2; ++grp) {
            f32x4 acc[4] = {};
            #pragma unroll
            for (int kc = 0; kc < 8; ++kc) {
                #pragma unroll
                for (int u = 0; u < 4; ++u) {
                    bf16x8 wf = *(const bf16x8*)(Wz + (och * 128 + (grp * 4 + u) * 16 + l16) * CCH + kc * 32 + quad * 8);
                    acc[u] = __builtin_amdgcn_mfma_f32_16x16x32_bf16(wf, xf[kc], acc[u], 0, 0, 0);
                }
            }
            #pragma unroll
            for (int u = 0; u < 4; ++u) {
                const int ot = och * 8 + grp * 4 + u;
                f32x4 bz = *(const f32x4*)(bias + och * 128 + (grp * 4 + u) * 16 + quad * 4);
                bf16x4 o;
                o[0] = (__bf16)(acc[u][0] + bz[0] * qs);
                o[1] = (__bf16)(acc[u][1] + bz[1] * qs);
                o[2] = (__bf16)(acc[u][2] + bz[2] * qs);
                o[3] = (__bf16)(acc[u][3] + bz[3] * qs);
                const int head = ot >> 2, dloc = (ot & 3) * 16 + quad * 4;
                *(bf16x4*)(dst + head * (NPIX * HD) + (p0 + pw + l16) * HD + dloc) = o;
            }
        }
    } else {
        #pragma unroll
        for (int grp = 0; grp < 2; ++grp) {
            f32x4 acc[4] = {};
            #pragma unroll
            for (int kc = 0; kc < 8; ++kc) {
                #pragma unroll
                for (int u = 0; u < 4; ++u) {
                    bf16x8 wf = *(const bf16x8*)(Wz + (och * 128 + (grp * 4 + u) * 16 + l16) * CCH + kc * 32 + quad * 8);
                    acc[u] = __builtin_amdgcn_mfma_f32_16x16x32_bf16(xf[kc], wf, acc[u], 0, 0, 0);
                }
            }
            #pragma unroll
            for (int u = 0; u < 4; ++u) {
                const int oc = och * 128 + (grp * 4 + u) * 16 + l16;
                const float bz = bias[oc];
                bf16x4 o;
                o[0] = (__bf16)(acc[u][0] + bz); o[1] = (__bf16)(acc[u][1] + bz);
                o[2] = (__bf16)(acc[u][2] + bz); o[3] = (__bf16)(acc[u][3] + bz);
                *(bf16x4*)(Vb + oc * NPIX + p0 + pw + quad * 4) = o;
            }
        }
    }
}

// ---------------------------------------------------------------------------
// K2 (R19): BARRIER-FREE DMA-pipelined attention. R17 (attn 39->33, win)
// kept 2 s_barrier/tile only because V staging was cross-wave (wave stages
// 16 d-rows, reads all 64). R18's co-resident-block dovetail nulled because
// R17's waves are barrier-locked in lockstep (all stall at the same points).
// R19 re-partitions V staging by KEY-SLICE: each wave stages all 64 d-rows
// x its own 32 keys (4KB; same totals, same DMA count) -> K and V are both
// wave-private -> ZERO barriers in the main loop; ordering is per-wave
// vmcnt(8) only. The 4 waves drift freely and fill each other's stalls
// (the dovetail R18 wanted, for free). WAR on re-stage is safe: ds_reads
// enter the LDS pipe at issue, the re-stage DMA's write returns from L2
// hundreds of cycles later, and compiler preserves read->write program
// order on the same addresses.
// V swizzle (64B rows): LDS[row][c16] = V[row][c16 ^ ((row>>2)&3)], staged
// via pre-swizzled global chunk (lane&3)^(lane>>4), read at quad^(l16>>2);
// involution checked: read == V[row][quad] exactly. K path, compute core,
// epilogue byte-identical to green R17.
// ---------------------------------------------------------------------------
#define OFFK0 0
#define OFFK1 16384
#define OFFV0 32768
#define OFFV1 49152
#define SMEMSZ 70656   // max(64K buffers, 69632 co + 1024 cl) via overlay

__global__ __launch_bounds__(256, 1) void attn_mfma(
    const __bf16* __restrict__ Qb, const __bf16* __restrict__ Kb,
    const __bf16* __restrict__ Vb, __bf16* __restrict__ Sb)
{
    __shared__ __align__(16) char smem[SMEMSZ];

    const int t = threadIdx.x, lane = t & 63, wave = t >> 6;
    const int l16 = lane & 15, quad = lane >> 4;

    const int bid  = blockIdx.x;
    const int head = (bid & 7) >> 1;                   // XCD-pair pinning
    const int qt   = ((bid >> 3) << 1) | (bid & 1);    // 0..63
    const int p0   = qt * 64;

    const __bf16* Qh = Qb + head * (NPIX * HD);

    // Q B-frags for 64 shared rows: B[k=d][n=row16]
    bf16x8 qf[4][2];
    #pragma unroll
    for (int rt = 0; rt < 4; ++rt) {
        const __bf16* qp = Qh + (p0 + rt * 16 + l16) * HD + quad * 8;
        qf[rt][0] = *(const bf16x8*)(qp);
        qf[rt][1] = *(const bf16x8*)(qp + 32);
    }

    bf16x8 ones;
    #pragma unroll
    for (int j = 0; j < 8; ++j) ones[j] = (__bf16)1.0f;

    f32x4 l_acc[4] = {};
    f32x4 o_acc[4][4] = {};   // [dt][rt]

    // ---- staging (8 DMA instr / wave / tile), fully wave-private ----
    const int lr3 = lane >> 3, lc3 = lane & 7;     // K: row-in-chunk, col-chunk
    const int kcol = ((lc3 ^ lr3) << 4);           // K pre-swizzled global col
    const int vrow = lane >> 2;                    // V: d-row within instr group
    const int vchk = (((lane & 3) ^ (lane >> 4)) << 4);  // V pre-swizzled chunk
    const char* Kg = (const char*)(Kb + (head * NPIX) * HD);
    const char* Vg = (const char*)(Vb + (head * HD) * NPIX);

    auto stageK = [&](int it, int b) {
        char* dst = smem + (b ? OFFK1 : OFFK0) + wave * 4096;  // wave's 32 rows
        const char* src = Kg + (it * 128 + wave * 32) * 128;   // 128 B / K-row
        #pragma unroll
        for (int i = 0; i < 4; ++i)
            gload_lds16(src + (i * 8 + lr3) * 128 + kcol, dst + i * 1024);
    };
    auto stageV = [&](int it, int b) {
        // wave-private: all 64 d-rows x wave's 32 keys (64 B/row)
        char* dst = smem + (b ? OFFV1 : OFFV0) + wave * 4096;
        const char* src = Vg + it * 256 + wave * 64;
        #pragma unroll
        for (int i = 0; i < 4; ++i)
            gload_lds16(src + (i * 16 + vrow) * (NPIX * 2) + vchk, dst + i * 1024);
    };

    // S^T = K Q^T : C(key_local = kt*16+quad*4+r, row = rt*16+l16)
    auto qk = [&](bf16x8 k0, bf16x8 k1, bf16x8 k2, bf16x8 k3,
                  f32x4 (&s0)[4], f32x4 (&s1)[4]) {
        #pragma unroll
        for (int rt = 0; rt < 4; ++rt) {
            s0[rt] = f32x4{0.f, 0.f, 0.f, 0.f};
            s1[rt] = f32x4{0.f, 0.f, 0.f, 0.f};
            s0[rt] = __builtin_amdgcn_mfma_f32_16x16x32_bf16(k0, qf[rt][0], s0[rt], 0, 0, 0);
            s0[rt] = __builtin_amdgcn_mfma_f32_16x16x32_bf16(k1, qf[rt][1], s0[rt], 0, 0, 0);
            s1[rt] = __builtin_amdgcn_mfma_f32_16x16x32_bf16(k2, qf[rt][0], s1[rt], 0, 0, 0);
            s1[rt] = __builtin_amdgcn_mfma_f32_16x16x32_bf16(k3, qf[rt][1], s1[rt], 0, 0, 0);
        }
    };

    auto pvx = [&](const f32x4 (&s0)[4], const f32x4 (&s1)[4],
                   bf16x8 v0, bf16x8 v1, bf16x8 v2, bf16x8 v3) {
        #pragma unroll
        for (int rt = 0; rt < 4; ++rt) {
            unsigned a0 = pack_bf16x2(EXP2(s0[rt][0]), EXP2(s0[rt][1]));
            unsigned a1 = pack_bf16x2(EXP2(s0[rt][2]), EXP2(s0[rt][3]));
            unsigned b0 = pack_bf16x2(EXP2(s1[rt][0]), EXP2(s1[rt][1]));
            unsigned b1 = pack_bf16x2(EXP2(s1[rt][2]), EXP2(s1[rt][3]));
            // swap32 then swap16: (a0,b0) -> (w0,w2); (a1,b1) -> (w1,w3)
            asm("v_permlane32_swap_b32 %0, %1" : "+v"(a0), "+v"(b0));
            asm("v_permlane32_swap_b32 %0, %1" : "+v"(a1), "+v"(b1));
            asm("v_permlane16_swap_b32 %0, %1" : "+v"(a0), "+v"(b0));
            asm("v_permlane16_swap_b32 %0, %1" : "+v"(a1), "+v"(b1));
            uint32x4 w;
            w[0] = a0; w[1] = a1; w[2] = b0; w[3] = b1;
            const bf16x8 bp = __builtin_bit_cast(bf16x8, w);  // B[k=key32][n=row]
            l_acc[rt] = __builtin_amdgcn_mfma_f32_16x16x32_bf16(ones, bp, l_acc[rt], 0, 0, 0);
            o_acc[0][rt] = __builtin_amdgcn_mfma_f32_16x16x32_bf16(v0, bp, o_acc[0][rt], 0, 0, 0);
            o_acc[1][rt] = __builtin_amdgcn_mfma_f32_16x16x32_bf16(v1, bp, o_acc[1][rt], 0, 0, 0);
            o_acc[2][rt] = __builtin_amdgcn_mfma_f32_16x16x32_bf16(v2, bp, o_acc[2][rt], 0, 0, 0);
            o_acc[3][rt] = __builtin_amdgcn_mfma_f32_16x16x32_bf16(v3, bp, o_acc[3][rt], 0, 0, 0);
        }
    };

    // prologue: tiles 0 and 1 in flight (16 DMAs)
    stageK(0, 0); stageV(0, 0);
    stageK(1, 1); stageV(1, 1);

    const int ksw = ((l16 & 7) << 4);
    const int vsw = ((quad ^ (l16 >> 2)) << 4);

    #pragma unroll 1
    for (int it = 0; it < 32; ++it) {
        const int b = it & 1;
        if (it == 31) asm volatile("s_waitcnt vmcnt(0)" ::: "memory");
        else          asm volatile("s_waitcnt vmcnt(8)" ::: "memory");
        __builtin_amdgcn_sched_barrier(0);

        const char* bk = smem + (b ? OFFK1 : OFFK0);
        const char* bv = smem + (b ? OFFV1 : OFFV0) + wave * 4096;

        // K frags (swizzled read; wave's own 32 rows)
        const int kr0 = (wave * 32 + l16) * 128;
        bf16x8 k0 = *(const bf16x8*)(bk + kr0 + ((quad * 16) ^ ksw));
        bf16x8 k1 = *(const bf16x8*)(bk + kr0 + ((64 + quad * 16) ^ ksw));
        bf16x8 k2 = *(const bf16x8*)(bk + kr0 + 2048 + ((quad * 16) ^ ksw));
        bf16x8 k3 = *(const bf16x8*)(bk + kr0 + 2048 + ((64 + quad * 16) ^ ksw));
        // V frags (swizzled read; wave-private 64 d-rows x 64B key slice)
        bf16x8 v0 = *(const bf16x8*)(bv + (l16) * 64 + vsw);
        bf16x8 v1 = *(const bf16x8*)(bv + (16 + l16) * 64 + vsw);
        bf16x8 v2 = *(const bf16x8*)(bv + (32 + l16) * 64 + vsw);
        bf16x8 v3 = *(const bf16x8*)(bv + (48 + l16) * 64 + vsw);

        f32x4 s0[4], s1[4];
        qk(k0, k1, k2, k3, s0, s1);
        pvx(s0, s1, v0, v1, v2, v3);

        if (it < 30) { stageK(it + 2, b); stageV(it + 2, b); }
    }

    // ---- in-LDS 4-way key merge (overlay over the K/V buffers) ----
    __syncthreads();   // waves drift in the barrier-free loop; align before overlay
    float* co = (float*)smem;
    float* cl = (float*)(smem + 69632);

    #pragma unroll
    for (int dt = 0; dt < 4; ++dt)
        #pragma unroll
        for (int rt = 0; rt < 4; ++rt)
            *(f32x4*)(co + wave * 4352 + (rt * 16 + l16) * 68 + dt * 16 + quad * 4) = o_acc[dt][rt];
    if (quad == 0) {
        #pragma unroll
        for (int rt = 0; rt < 4; ++rt)
            cl[wave * 64 + rt * 16 + l16] = l_acc[rt][0];
    }
    __syncthreads();

    {
        const int row = t >> 2, dc = (t & 3) * 16;
        const float l = cl[row] + cl[64 + row] + cl[128 + row] + cl[192 + row];
        const float inv = 1.f / l;
        f32x4 s[4];
        #pragma unroll
        for (int j = 0; j < 4; ++j) {
            s[j] = f32x4{0.f, 0.f, 0.f, 0.f};
            #pragma unroll
            for (int w = 0; w < 4; ++w)
                s[j] += *(const f32x4*)(co + w * 4352 + row * 68 + dc + j * 4);
        }
        bf16x8 o1, o2;
        #pragma unroll
        for (int j = 0; j < 4; ++j) {
            o1[j]     = (__bf16)(s[0][j] * inv);
            o1[j + 4] = (__bf16)(s[1][j] * inv);
            o2[j]     = (__bf16)(s[2][j] * inv);
            o2[j + 4] = (__bf16)(s[3][j] * inv);
        }
        __bf16* dst = Sb + (p0 + row) * CCH + head * HD + dc;
        *(bf16x8*)(dst)     = o1;
        *(bf16x8*)(dst + 8) = o2;
    }
}

// ---------------------------------------------------------------------------
// K3: proj bf16 MFMA GEMM + bias + residual, fp32 out [c][pix].
// (R12/R17-proven Sb-based version)
// ---------------------------------------------------------------------------
__global__ __launch_bounds__(256) void gemm_proj(
    const __bf16* __restrict__ Sb, const __bf16* __restrict__ Wpb,
    const float* __restrict__ bias, const float* __restrict__ X,
    float* __restrict__ Out)
{
    __shared__ __bf16 Bs[32 * XPITCH];

    const int t = threadIdx.x, lane = t & 63, wave = t >> 6;
    const int l16 = lane & 15, quad = lane >> 4;
    const int p0  = blockIdx.x * 32;
    const int och = blockIdx.y;

    #pragma unroll
    for (int pg = 0; pg < 4; ++pg) {
        bf16x8 v = *(const bf16x8*)(Sb + t * NPIX + p0 + pg * 8);
        #pragma unroll
        for (int j = 0; j < 8; ++j)
            Bs[(pg * 8 + j) * XPITCH + t] = v[j];
    }
    __syncthreads();

    const int pixset = wave & 1, ocset = wave >> 1;
    bf16x8 af[8];
    #pragma unroll
    for (int kc = 0; kc < 8; ++kc)
        af[kc] = *(const bf16x8*)(Bs + (pixset * 16 + l16) * XPITCH + kc * 32 + quad * 8);

    #pragma unroll
    for (int u = 0; u < 4; ++u) {
        f32x4 acc = {};
        const int oc_t = och * 128 + ocset * 64 + u * 16;
        #pragma unroll
        for (int kc = 0; kc < 8; ++kc) {
            bf16x8 wf = *(const bf16x8*)(Wpb + (oc_t + l16) * CCH + kc * 32 + quad * 8);
            acc = __builtin_amdgcn_mfma_f32_16x16x32_bf16(af[kc], wf, acc, 0, 0, 0);
        }
        const int oc  = oc_t + l16;
        const int pix = p0 + pixset * 16 + quad * 4;
        const float bz = bias[oc];
        f32x4 r4 = *(const f32x4*)(X + oc * NPIX + pix);
        f32x4 y;
        y[0] = acc[0] + bz + r4[0];
        y[1] = acc[1] + bz + r4[1];
        y[2] = acc[2] + bz + r4[2];
        y[3] = acc[3] + bz + r4[3];
        *(f32x4*)(Out + oc * NPIX + pix) = y;
    }
}

// ---------------------------------------------------------------------------
extern "C" void kernel_launch(void* const* d_in, const int* in_sizes, int n_in,
                              void* d_out, int out_size, void* d_ws, size_t ws_size,
                              hipStream_t stream)
{
    const float* x     = (const float*)d_in[0];
    const float* gamma = (const float*)d_in[1];
    const float* beta  = (const float*)d_in[2];
    const float* Wq    = (const float*)d_in[3];
    const float* bq    = (const float*)d_in[4];
    const float* Wk    = (const float*)d_in[5];
    const float* bk    = (const float*)d_in[6];
    const float* Wv    = (const float*)d_in[7];
    const float* bv    = (const float*)d_in[8];
    const float* Wp    = (const float*)d_in[9];
    const float* bp    = (const float*)d_in[10];
    float* out = (float*)d_out;

    char* ws = (char*)d_ws;
    float*  psum = (float*)(ws);                // 1KB stats partial sums
    float*  pssq = (float*)(ws + 1024);         // 1KB
    __bf16* Wb   = (__bf16*)(ws + 65536);       // 512KB bf16 4x[256][256]
    __bf16* Qb   = (__bf16*)(ws + (1 << 20));   // 2MB bf16 [head][pix][64]
    __bf16* Kb   = (__bf16*)(ws + (3 << 20));   // 2MB bf16 [head][pix][64]
    __bf16* Vb   = (__bf16*)(ws + (5 << 20));   // 2MB bf16 [c][pix]
    __bf16* Sb   = (__bf16*)(ws + (7 << 20));   // 2MB bf16 flat F

    stats_wconv<<<320, 256, 0, stream>>>(x, Wq, Wk, Wv, Wp, psum, pssq, Wb);

    dim3 gq(64, 6);
    gn_qkv<<<gq, 256, 0, stream>>>(x, gamma, beta, psum, pssq, Wb,
                                   bq, bk, bv, Qb, Kb, Vb);

    attn_mfma<<<256, 256, 0, stream>>>(Qb, Kb, Vb, Sb);

    dim3 gp(128, 2);
    gemm_proj<<<gp, 256, 0, stream>>>(Sb, Wb + 3 * 65536, bp, x, out);
}

// Round 12
// 129.908 us; speedup vs baseline: 1.0695x; 1.0245x over previous
//
#include <hip/hip_runtime.h>
#include <hip/hip_bf16.h>

// b=1, c=256, h=w=64 -> n=4096 pixels, 4 heads, hd=64, 32 groups x 8 ch.
// scale = hd^-0.5 * log2(e) = 0.18033688, folded into Wq (K0) and bq (K1
// epilogue) so attention softmax uses native v_exp_f32 (exp2) directly.
#define NPIX 4096
#define CCH  256
#define HD   64
#define GSIZE 32768   // 8 ch * 4096 pix per group

#define QSCALE 0.18033688f   // 0.125 * log2(e); softmax in base-2 domain

typedef __bf16 bf16x8 __attribute__((ext_vector_type(8)));
typedef __bf16 bf16x4 __attribute__((ext_vector_type(4)));
typedef __bf16 bf16x2 __attribute__((ext_vector_type(2)));
typedef float  f32x4  __attribute__((ext_vector_type(4)));
typedef unsigned int uint32x4 __attribute__((ext_vector_type(4)));

#define XPITCH 264   // X/F panel pitch (bf16) for K1/K3

#if __has_builtin(__builtin_amdgcn_exp2f)
#define EXP2(x) __builtin_amdgcn_exp2f(x)
#else
#define EXP2(x) __expf((x) * 0.6931471805599453f)
#endif

// MFMA 16x16x32_bf16 layouts (verified m89/m91):
//   A[m=lane&15][k=quad*8+j]; B[k=quad*8+j][n=lane&15]; C: row=quad*4+reg, col=lane&15

__device__ __forceinline__ unsigned pack_bf16x2(float lo, float hi)
{
    bf16x2 v;
    v[0] = (__bf16)lo;
    v[1] = (__bf16)hi;
    return __builtin_bit_cast(unsigned, v);
}

// direct global->LDS DMA, 16B per lane; LDS dest = wave-uniform base + lane*16
__device__ __forceinline__ void gload_lds16(const void* g, void* l)
{
    __builtin_amdgcn_global_load_lds(
        (const __attribute__((address_space(1))) void*)g,
        (__attribute__((address_space(3))) void*)l, 16, 0, 0);
}

// ---------------------------------------------------------------------------
// K0: blocks 0..255: per-(group,1/8th) partial sums -> psum/pssq[256].
//     blocks 256..319: weight fp32->bf16 convert (Wq scaled by QSCALE).
// ---------------------------------------------------------------------------
__global__ __launch_bounds__(256) void stats_wconv(
    const float* __restrict__ X,
    const float* __restrict__ Wq, const float* __restrict__ Wk,
    const float* __restrict__ Wv, const float* __restrict__ Wp,
    float* __restrict__ psum, float* __restrict__ pssq, __bf16* __restrict__ Wb)
{
    const int bid = blockIdx.x, t = threadIdx.x;
    if (bid < 256) {
        const float* base = X + bid * 4096;   // (g = bid>>3, seg = bid&7)
        float sum = 0.f, ssq = 0.f;
        #pragma unroll
        for (int k = 0; k < 4; ++k) {
            float4 v = *(const float4*)(base + t * 4 + k * 1024);
            sum += v.x + v.y + v.z + v.w;
            ssq += v.x * v.x + v.y * v.y + v.z * v.z + v.w * v.w;
        }
        #pragma unroll
        for (int off = 1; off < 64; off <<= 1) {
            sum += __shfl_xor(sum, off);
            ssq += __shfl_xor(ssq, off);
        }
        __shared__ float red[2][4];
        const int wv = t >> 6;
        if ((t & 63) == 0) { red[0][wv] = sum; red[1][wv] = ssq; }
        __syncthreads();
        if (t == 0) {
            psum[bid] = red[0][0] + red[0][1] + red[0][2] + red[0][3];
            pssq[bid] = red[1][0] + red[1][1] + red[1][2] + red[1][3];
        }
    } else {
        const int j0 = (bid - 256) * 4096 + t * 16;
        const int m  = j0 >> 16;
        const float* W = (m == 0) ? Wq : (m == 1) ? Wk : (m == 2) ? Wv : Wp;
        const float sc = (m == 0) ? QSCALE : 1.f;
        const int off = j0 & 65535;
        #pragma unroll
        for (int k = 0; k < 4; ++k) {
            float4 v = *(const float4*)(W + off + k * 4);
            bf16x4 o;
            o[0] = (__bf16)(v.x * sc); o[1] = (__bf16)(v.y * sc);
            o[2] = (__bf16)(v.z * sc); o[3] = (__bf16)(v.w * sc);
            *(bf16x4*)(Wb + m * 65536 + off + k * 4) = o;
        }
    }
}

// ---------------------------------------------------------------------------
// K1: fused GroupNorm-apply + QKV MFMA GEMM. grid (64 pixblk, 6: z*2+och).
// (unchanged; qs = QSCALE)
// ---------------------------------------------------------------------------
__global__ __launch_bounds__(256) void gn_qkv(
    const float* __restrict__ X, const float* __restrict__ gamma,
    const float* __restrict__ beta,
    const float* __restrict__ psum, const float* __restrict__ pssq,
    const __bf16* __restrict__ Wb,
    const float* __restrict__ bq, const float* __restrict__ bk,
    const float* __restrict__ bv,
    __bf16* __restrict__ Qb, __bf16* __restrict__ Kb, __bf16* __restrict__ Vb)
{
    __shared__ __bf16 tile[64 * XPITCH];
    __shared__ float al[256], bl[256];

    const int t = threadIdx.x, lane = t & 63, wave = t >> 6;
    const int l16 = lane & 15, quad = lane >> 4;
    const int p0 = blockIdx.x * 64;
    const int z = blockIdx.y >> 1, och = blockIdx.y & 1;

    {
        const int g = t >> 3;
        float s = 0.f, q = 0.f;
        #pragma unroll
        for (int j = 0; j < 8; ++j) { s += psum[g * 8 + j]; q += pssq[g * 8 + j]; }
        const float mu  = s * (1.f / GSIZE);
        const float var = q * (1.f / GSIZE) - mu * mu;
        const float a = gamma[t] * rsqrtf(var + 1e-6f);
        al[t] = a;
        bl[t] = beta[t] - mu * a;
    }
    __syncthreads();

    #pragma unroll 4
    for (int i = 0; i < 16; ++i) {
        const int c4 = wave * 64 + i * 4;
        f32x4 a4 = *(const f32x4*)(al + c4);
        f32x4 b4 = *(const f32x4*)(bl + c4);
        bf16x4 pk;
        pk[0] = (__bf16)(X[(c4 + 0) * NPIX + p0 + lane] * a4[0] + b4[0]);
        pk[1] = (__bf16)(X[(c4 + 1) * NPIX + p0 + lane] * a4[1] + b4[1]);
        pk[2] = (__bf16)(X[(c4 + 2) * NPIX + p0 + lane] * a4[2] + b4[2]);
        pk[3] = (__bf16)(X[(c4 + 3) * NPIX + p0 + lane] * a4[3] + b4[3]);
        *(bf16x4*)(tile + lane * XPITCH + c4) = pk;
    }
    __syncthreads();

    const int pw = wave * 16;
    bf16x8 xf[8];
    #pragma unroll
    for (int kc = 0; kc < 8; ++kc)
        xf[kc] = *(const bf16x8*)(tile + (pw + l16) * XPITCH + kc * 32 + quad * 8);

    const __bf16* Wz = Wb + z * 65536;
    const float* bias = (z == 0) ? bq : (z == 1) ? bk : bv;

    if (z < 2) {
        const float qs = (z == 0) ? QSCALE : 1.f;
        __bf16* dst = (z == 0) ? Qb : Kb;
        #pragma unroll
        for (int grp = 0; grp < 2; ++grp) {
            f32x4 acc[4] = {};
            #pragma unroll
            for (int kc = 0; kc < 8; ++kc) {
                #pragma unroll
                for (int u = 0; u < 4; ++u) {
                    bf16x8 wf = *(const bf16x8*)(Wz + (och * 128 + (grp * 4 + u) * 16 + l16) * CCH + kc * 32 + quad * 8);
                    acc[u] = __builtin_amdgcn_mfma_f32_16x16x32_bf16(wf, xf[kc], acc[u], 0, 0, 0);
                }
            }
            #pragma unroll
            for (int u = 0; u < 4; ++u) {
                const int ot = och * 8 + grp * 4 + u;
                f32x4 bz = *(const f32x4*)(bias + och * 128 + (grp * 4 + u) * 16 + quad * 4);
                bf16x4 o;
                o[0] = (__bf16)(acc[u][0] + bz[0] * qs);
                o[1] = (__bf16)(acc[u][1] + bz[1] * qs);
                o[2] = (__bf16)(acc[u][2] + bz[2] * qs);
                o[3] = (__bf16)(acc[u][3] + bz[3] * qs);
                const int head = ot >> 2, dloc = (ot & 3) * 16 + quad * 4;
                *(bf16x4*)(dst + head * (NPIX * HD) + (p0 + pw + l16) * HD + dloc) = o;
            }
        }
    } else {
        #pragma unroll
        for (int grp = 0; grp < 2; ++grp) {
            f32x4 acc[4] = {};
            #pragma unroll
            for (int kc = 0; kc < 8; ++kc) {
                #pragma unroll
                for (int u = 0; u < 4; ++u) {
                    bf16x8 wf = *(const bf16x8*)(Wz + (och * 128 + (grp * 4 + u) * 16 + l16) * CCH + kc * 32 + quad * 8);
                    acc[u] = __builtin_amdgcn_mfma_f32_16x16x32_bf16(xf[kc], wf, acc[u], 0, 0, 0);
                }
            }
            #pragma unroll
            for (int u = 0; u < 4; ++u) {
                const int oc = och * 128 + (grp * 4 + u) * 16 + l16;
                const float bz = bias[oc];
                bf16x4 o;
                o[0] = (__bf16)(acc[u][0] + bz); o[1] = (__bf16)(acc[u][1] + bz);
                o[2] = (__bf16)(acc[u][2] + bz); o[3] = (__bf16)(acc[u][3] + bz);
                *(bf16x4*)(Vb + oc * NPIX + p0 + pw + quad * 4) = o;
            }
        }
    }
}

// ---------------------------------------------------------------------------
// K2 (R20): 512-thread, 8-wave, barrier-free DMA attention = 2 waves/SIMD.
// R19 post-mortem: the 4 waves of a 256-thread block sit on 4 DIFFERENT
// SIMDs -> R19's win was only barrier removal; each SIMD still hosts ONE
// wave, whose vmcnt/dep-chain stalls are unfillable (~30 us vs ~14 floor).
// R20: one 512-thread block per CU; 8 waves split a 256-key tile 8 ways
// (identical per-wave fragment shape, 16 tiles of 256 keys). All staging
// wave-private, loop zero-barrier -> the 2 waves on each SIMD drift freely
// and dovetail (one issues MFMA while the other waits at vmcnt). Merge is
// in-LDS 8-way (no fp32 global partials, K3 untouched). LDS: 2x(32K K +
// 32K V) = 128 KB buffers; merge overlay 141312 B <= 160 KB -> 1 block/CU.
// Per-CU DMA count, traffic, MFMA totals identical to R19; the only new
// variable is waves/SIMD with an allocator-proof pipeline.
// ---------------------------------------------------------------------------
#define OFFK0 0
#define OFFK1 32768
#define OFFV0 65536
#define OFFV1 98304
#define SMEMSZ 141312  // max(128K buffers, 139264 co + 2048 cl) via overlay

__global__ __launch_bounds__(512, 2) void attn_mfma(
    const __bf16* __restrict__ Qb, const __bf16* __restrict__ Kb,
    const __bf16* __restrict__ Vb, __bf16* __restrict__ Sb)
{
    __shared__ __align__(16) char smem[SMEMSZ];

    const int t = threadIdx.x, lane = t & 63, wave = t >> 6;   // wave 0..7
    const int l16 = lane & 15, quad = lane >> 4;

    const int bid  = blockIdx.x;
    const int head = (bid & 7) >> 1;                   // XCD-pair pinning
    const int qt   = ((bid >> 3) << 1) | (bid & 1);    // 0..63
    const int p0   = qt * 64;

    const __bf16* Qh = Qb + head * (NPIX * HD);

    // Q B-frags for 64 shared rows: B[k=d][n=row16]
    bf16x8 qf[4][2];
    #pragma unroll
    for (int rt = 0; rt < 4; ++rt) {
        const __bf16* qp = Qh + (p0 + rt * 16 + l16) * HD + quad * 8;
        qf[rt][0] = *(const bf16x8*)(qp);
        qf[rt][1] = *(const bf16x8*)(qp + 32);
    }

    bf16x8 ones;
    #pragma unroll
    for (int j = 0; j < 8; ++j) ones[j] = (__bf16)1.0f;

    f32x4 l_acc[4] = {};
    f32x4 o_acc[4][4] = {};   // [dt][rt]

    // ---- staging (8 DMA instr / wave / tile), fully wave-private ----
    // wave owns keys [wave*32, wave*32+32) of each 256-key tile
    const int lr3 = lane >> 3, lc3 = lane & 7;     // K: row-in-chunk, col-chunk
    const int kcol = ((lc3 ^ lr3) << 4);           // K pre-swizzled global col
    const int vrow = lane >> 2;                    // V: d-row within instr group
    const int vchk = (((lane & 3) ^ (lane >> 4)) << 4);  // V pre-swizzled chunk
    const char* Kg = (const char*)(Kb + (head * NPIX) * HD);
    const char* Vg = (const char*)(Vb + (head * HD) * NPIX);

    auto stageK = [&](int it, int b) {
        char* dst = smem + (b ? OFFK1 : OFFK0) + wave * 4096;   // wave's 32 rows
        const char* src = Kg + (it * 256 + wave * 32) * 128;    // 128 B / K-row
        #pragma unroll
        for (int i = 0; i < 4; ++i)
            gload_lds16(src + (i * 8 + lr3) * 128 + kcol, dst + i * 1024);
    };
    auto stageV = [&](int it, int b) {
        // wave-private: all 64 d-rows x wave's 32 keys (64 B/row)
        char* dst = smem + (b ? OFFV1 : OFFV0) + wave * 4096;
        const char* src = Vg + it * 512 + wave * 64;
        #pragma unroll
        for (int i = 0; i < 4; ++i)
            gload_lds16(src + (i * 16 + vrow) * (NPIX * 2) + vchk, dst + i * 1024);
    };

    // S^T = K Q^T : C(key_local = kt*16+quad*4+r, row = rt*16+l16)
    auto qk = [&](bf16x8 k0, bf16x8 k1, bf16x8 k2, bf16x8 k3,
                  f32x4 (&s0)[4], f32x4 (&s1)[4]) {
        #pragma unroll
        for (int rt = 0; rt < 4; ++rt) {
            s0[rt] = f32x4{0.f, 0.f, 0.f, 0.f};
            s1[rt] = f32x4{0.f, 0.f, 0.f, 0.f};
            s0[rt] = __builtin_amdgcn_mfma_f32_16x16x32_bf16(k0, qf[rt][0], s0[rt], 0, 0, 0);
            s0[rt] = __builtin_amdgcn_mfma_f32_16x16x32_bf16(k1, qf[rt][1], s0[rt], 0, 0, 0);
            s1[rt] = __builtin_amdgcn_mfma_f32_16x16x32_bf16(k2, qf[rt][0], s1[rt], 0, 0, 0);
            s1[rt] = __builtin_amdgcn_mfma_f32_16x16x32_bf16(k3, qf[rt][1], s1[rt], 0, 0, 0);
        }
    };

    auto pvx = [&](const f32x4 (&s0)[4], const f32x4 (&s1)[4],
                   bf16x8 v0, bf16x8 v1, bf16x8 v2, bf16x8 v3) {
        #pragma unroll
        for (int rt = 0; rt < 4; ++rt) {
            unsigned a0 = pack_bf16x2(EXP2(s0[rt][0]), EXP2(s0[rt][1]));
            unsigned a1 = pack_bf16x2(EXP2(s0[rt][2]), EXP2(s0[rt][3]));
            unsigned b0 = pack_bf16x2(EXP2(s1[rt][0]), EXP2(s1[rt][1]));
            unsigned b1 = pack_bf16x2(EXP2(s1[rt][2]), EXP2(s1[rt][3]));
            // swap32 then swap16: (a0,b0) -> (w0,w2); (a1,b1) -> (w1,w3)
            asm("v_permlane32_swap_b32 %0, %1" : "+v"(a0), "+v"(b0));
            asm("v_permlane32_swap_b32 %0, %1" : "+v"(a1), "+v"(b1));
            asm("v_permlane16_swap_b32 %0, %1" : "+v"(a0), "+v"(b0));
            asm("v_permlane16_swap_b32 %0, %1" : "+v"(a1), "+v"(b1));
            uint32x4 w;
            w[0] = a0; w[1] = a1; w[2] = b0; w[3] = b1;
            const bf16x8 bp = __builtin_bit_cast(bf16x8, w);  // B[k=key32][n=row]
            l_acc[rt] = __builtin_amdgcn_mfma_f32_16x16x32_bf16(ones, bp, l_acc[rt], 0, 0, 0);
            o_acc[0][rt] = __builtin_amdgcn_mfma_f32_16x16x32_bf16(v0, bp, o_acc[0][rt], 0, 0, 0);
            o_acc[1][rt] = __builtin_amdgcn_mfma_f32_16x16x32_bf16(v1, bp, o_acc[1][rt], 0, 0, 0);
            o_acc[2][rt] = __builtin_amdgcn_mfma_f32_16x16x32_bf16(v2, bp, o_acc[2][rt], 0, 0, 0);
            o_acc[3][rt] = __builtin_amdgcn_mfma_f32_16x16x32_bf16(v3, bp, o_acc[3][rt], 0, 0, 0);
        }
    };

    // prologue: tiles 0 and 1 in flight (16 DMAs / wave)
    stageK(0, 0); stageV(0, 0);
    stageK(1, 1); stageV(1, 1);

    const int ksw = ((l16 & 7) << 4);
    const int vsw = ((quad ^ (l16 >> 2)) << 4);

    #pragma unroll 1
    for (int it = 0; it < 16; ++it) {
        const int b = it & 1;
        if (it == 15) asm volatile("s_waitcnt vmcnt(0)" ::: "memory");
        else          asm volatile("s_waitcnt vmcnt(8)" ::: "memory");
        __builtin_amdgcn_sched_barrier(0);

        const char* bk = smem + (b ? OFFK1 : OFFK0) + wave * 4096;
        const char* bv = smem + (b ? OFFV1 : OFFV0) + wave * 4096;

        // K frags (swizzled read; wave's own 32 rows)
        const int kr0 = l16 * 128;
        bf16x8 k0 = *(const bf16x8*)(bk + kr0 + ((quad * 16) ^ ksw));
        bf16x8 k1 = *(const bf16x8*)(bk + kr0 + ((64 + quad * 16) ^ ksw));
        bf16x8 k2 = *(const bf16x8*)(bk + kr0 + 2048 + ((quad * 16) ^ ksw));
        bf16x8 k3 = *(const bf16x8*)(bk + kr0 + 2048 + ((64 + quad * 16) ^ ksw));
        // V frags (swizzled read; wave-private 64 d-rows x 64B key slice)
        bf16x8 v0 = *(const bf16x8*)(bv + (l16) * 64 + vsw);
        bf16x8 v1 = *(const bf16x8*)(bv + (16 + l16) * 64 + vsw);
        bf16x8 v2 = *(const bf16x8*)(bv + (32 + l16) * 64 + vsw);
        bf16x8 v3 = *(const bf16x8*)(bv + (48 + l16) * 64 + vsw);

        f32x4 s0[4], s1[4];
        qk(k0, k1, k2, k3, s0, s1);
        pvx(s0, s1, v0, v1, v2, v3);

        if (it < 14) { stageK(it + 2, b); stageV(it + 2, b); }
    }

    // ---- in-LDS 8-way key merge (overlay over the K/V buffers) ----
    __syncthreads();   // waves drift in the barrier-free loop; align before overlay
    float* co = (float*)smem;                  // 8 x 64 x 68 f32 = 139264 B
    float* cl = (float*)(smem + 139264);       // 8 x 64 f32

    #pragma unroll
    for (int dt = 0; dt < 4; ++dt)
        #pragma unroll
        for (int rt = 0; rt < 4; ++rt)
            *(f32x4*)(co + wave * 4352 + (rt * 16 + l16) * 68 + dt * 16 + quad * 4) = o_acc[dt][rt];
    if (quad == 0) {
        #pragma unroll
        for (int rt = 0; rt < 4; ++rt)
            cl[wave * 64 + rt * 16 + l16] = l_acc[rt][0];
    }
    __syncthreads();

    {
        const int row = t >> 3, dc = (t & 7) * 8;   // 512 thr: 64 rows x 8 d each
        float l = 0.f;
        #pragma unroll
        for (int w = 0; w < 8; ++w) l += cl[w * 64 + row];
        const float inv = 1.f / l;
        f32x4 s0 = {0.f, 0.f, 0.f, 0.f}, s1 = {0.f, 0.f, 0.f, 0.f};
        #pragma unroll
        for (int w = 0; w < 8; ++w) {
            s0 += *(const f32x4*)(co + w * 4352 + row * 68 + dc);
            s1 += *(const f32x4*)(co + w * 4352 + row * 68 + dc + 4);
        }
        bf16x8 o;
        #pragma unroll
        for (int j = 0; j < 4; ++j) {
            o[j]     = (__bf16)(s0[j] * inv);
            o[j + 4] = (__bf16)(s1[j] * inv);
        }
        *(bf16x8*)(Sb + (p0 + row) * CCH + head * HD + dc) = o;
    }
}

// ---------------------------------------------------------------------------
// K3: proj bf16 MFMA GEMM + bias + residual, fp32 out [c][pix].
// (R12/R17-proven Sb-based version)
// ---------------------------------------------------------------------------
__global__ __launch_bounds__(256) void gemm_proj(
    const __bf16* __restrict__ Sb, const __bf16* __restrict__ Wpb,
    const float* __restrict__ bias, const float* __restrict__ X,
    float* __restrict__ Out)
{
    __shared__ __bf16 Bs[32 * XPITCH];

    const int t = threadIdx.x, lane = t & 63, wave = t >> 6;
    const int l16 = lane & 15, quad = lane >> 4;
    const int p0  = blockIdx.x * 32;
    const int och = blockIdx.y;

    #pragma unroll
    for (int pg = 0; pg < 4; ++pg) {
        bf16x8 v = *(const bf16x8*)(Sb + t * NPIX + p0 + pg * 8);
        #pragma unroll
        for (int j = 0; j < 8; ++j)
            Bs[(pg * 8 + j) * XPITCH + t] = v[j];
    }
    __syncthreads();

    const int pixset = wave & 1, ocset = wave >> 1;
    bf16x8 af[8];
    #pragma unroll
    for (int kc = 0; kc < 8; ++kc)
        af[kc] = *(const bf16x8*)(Bs + (pixset * 16 + l16) * XPITCH + kc * 32 + quad * 8);

    #pragma unroll
    for (int u = 0; u < 4; ++u) {
        f32x4 acc = {};
        const int oc_t = och * 128 + ocset * 64 + u * 16;
        #pragma unroll
        for (int kc = 0; kc < 8; ++kc) {
            bf16x8 wf = *(const bf16x8*)(Wpb + (oc_t + l16) * CCH + kc * 32 + quad * 8);
            acc = __builtin_amdgcn_mfma_f32_16x16x32_bf16(af[kc], wf, acc, 0, 0, 0);
        }
        const int oc  = oc_t + l16;
        const int pix = p0 + pixset * 16 + quad * 4;
        const float bz = bias[oc];
        f32x4 r4 = *(const f32x4*)(X + oc * NPIX + pix);
        f32x4 y;
        y[0] = acc[0] + bz + r4[0];
        y[1] = acc[1] + bz + r4[1];
        y[2] = acc[2] + bz + r4[2];
        y[3] = acc[3] + bz + r4[3];
        *(f32x4*)(Out + oc * NPIX + pix) = y;
    }
}

// ---------------------------------------------------------------------------
extern "C" void kernel_launch(void* const* d_in, const int* in_sizes, int n_in,
                              void* d_out, int out_size, void* d_ws, size_t ws_size,
                              hipStream_t stream)
{
    const float* x     = (const float*)d_in[0];
    const float* gamma = (const float*)d_in[1];
    const float* beta  = (const float*)d_in[2];
    const float* Wq    = (const float*)d_in[3];
    const float* bq    = (const float*)d_in[4];
    const float* Wk    = (const float*)d_in[5];
    const float* bk    = (const float*)d_in[6];
    const float* Wv    = (const float*)d_in[7];
    const float* bv    = (const float*)d_in[8];
    const float* Wp    = (const float*)d_in[9];
    const float* bp    = (const float*)d_in[10];
    float* out = (float*)d_out;

    char* ws = (char*)d_ws;
    float*  psum = (float*)(ws);                // 1KB stats partial sums
    float*  pssq = (float*)(ws + 1024);         // 1KB
    __bf16* Wb   = (__bf16*)(ws + 65536);       // 512KB bf16 4x[256][256]
    __bf16* Qb   = (__bf16*)(ws + (1 << 20));   // 2MB bf16 [head][pix][64]
    __bf16* Kb   = (__bf16*)(ws + (3 << 20));   // 2MB bf16 [head][pix][64]
    __bf16* Vb   = (__bf16*)(ws + (5 << 20));   // 2MB bf16 [c][pix]
    __bf16* Sb   = (__bf16*)(ws + (7 << 20));   // 2MB bf16 flat F

    stats_wconv<<<320, 256, 0, stream>>>(x, Wq, Wk, Wv, Wp, psum, pssq, Wb);

    dim3 gq(64, 6);
    gn_qkv<<<gq, 256, 0, stream>>>(x, gamma, beta, psum, pssq, Wb,
                                   bq, bk, bv, Qb, Kb, Vb);

    attn_mfma<<<256, 512, 0, stream>>>(Qb, Kb, Vb, Sb);

    dim3 gp(128, 2);
    gemm_proj<<<gp, 256, 0, stream>>>(Sb, Wb + 3 * 65536, bp, x, out);
}

// Round 13
// 129.377 us; speedup vs baseline: 1.0739x; 1.0041x over previous
//
#include <hip/hip_runtime.h>
#include <hip/hip_bf16.h>

// b=1, c=256, h=w=64 -> n=4096 pixels, 4 heads, hd=64, 32 groups x 8 ch.
// scale = hd^-0.5 * log2(e) = 0.18033688, folded into Wq (K0) and bq (K1
// epilogue) so attention softmax uses native v_exp_f32 (exp2) directly.
#define NPIX 4096
#define CCH  256
#define HD   64
#define GSIZE 32768   // 8 ch * 4096 pix per group

#define QSCALE 0.18033688f   // 0.125 * log2(e); softmax in base-2 domain

typedef __bf16 bf16x8 __attribute__((ext_vector_type(8)));
typedef __bf16 bf16x4 __attribute__((ext_vector_type(4)));
typedef __bf16 bf16x2 __attribute__((ext_vector_type(2)));
typedef float  f32x4  __attribute__((ext_vector_type(4)));
typedef unsigned int uint32x4 __attribute__((ext_vector_type(4)));

#define XPITCH 264   // X/F panel pitch (bf16) for K1/K3

#if __has_builtin(__builtin_amdgcn_exp2f)
#define EXP2(x) __builtin_amdgcn_exp2f(x)
#else
#define EXP2(x) __expf((x) * 0.6931471805599453f)
#endif

// MFMA 16x16x32_bf16 layouts (verified m89/m91):
//   A[m=lane&15][k=quad*8+j]; B[k=quad*8+j][n=lane&15]; C: row=quad*4+reg, col=lane&15

__device__ __forceinline__ unsigned pack_bf16x2(float lo, float hi)
{
    bf16x2 v;
    v[0] = (__bf16)lo;
    v[1] = (__bf16)hi;
    return __builtin_bit_cast(unsigned, v);
}

// direct global->LDS DMA, 16B per lane; LDS dest = wave-uniform base + lane*16
__device__ __forceinline__ void gload_lds16(const void* g, void* l)
{
    __builtin_amdgcn_global_load_lds(
        (const __attribute__((address_space(1))) void*)g,
        (__attribute__((address_space(3))) void*)l, 16, 0, 0);
}

// ---------------------------------------------------------------------------
// K0: blocks 0..255: per-(group,1/8th) partial sums -> psum/pssq[256].
//     blocks 256..319: weight fp32->bf16 convert (Wq scaled by QSCALE).
// ---------------------------------------------------------------------------
__global__ __launch_bounds__(256) void stats_wconv(
    const float* __restrict__ X,
    const float* __restrict__ Wq, const float* __restrict__ Wk,
    const float* __restrict__ Wv, const float* __restrict__ Wp,
    float* __restrict__ psum, float* __restrict__ pssq, __bf16* __restrict__ Wb)
{
    const int bid = blockIdx.x, t = threadIdx.x;
    if (bid < 256) {
        const float* base = X + bid * 4096;   // (g = bid>>3, seg = bid&7)
        float sum = 0.f, ssq = 0.f;
        #pragma unroll
        for (int k = 0; k < 4; ++k) {
            float4 v = *(const float4*)(base + t * 4 + k * 1024);
            sum += v.x + v.y + v.z + v.w;
            ssq += v.x * v.x + v.y * v.y + v.z * v.z + v.w * v.w;
        }
        #pragma unroll
        for (int off = 1; off < 64; off <<= 1) {
            sum += __shfl_xor(sum, off);
            ssq += __shfl_xor(ssq, off);
        }
        __shared__ float red[2][4];
        const int wv = t >> 6;
        if ((t & 63) == 0) { red[0][wv] = sum; red[1][wv] = ssq; }
        __syncthreads();
        if (t == 0) {
            psum[bid] = red[0][0] + red[0][1] + red[0][2] + red[0][3];
            pssq[bid] = red[1][0] + red[1][1] + red[1][2] + red[1][3];
        }
    } else {
        const int j0 = (bid - 256) * 4096 + t * 16;
        const int m  = j0 >> 16;
        const float* W = (m == 0) ? Wq : (m == 1) ? Wk : (m == 2) ? Wv : Wp;
        const float sc = (m == 0) ? QSCALE : 1.f;
        const int off = j0 & 65535;
        #pragma unroll
        for (int k = 0; k < 4; ++k) {
            float4 v = *(const float4*)(W + off + k * 4);
            bf16x4 o;
            o[0] = (__bf16)(v.x * sc); o[1] = (__bf16)(v.y * sc);
            o[2] = (__bf16)(v.z * sc); o[3] = (__bf16)(v.w * sc);
            *(bf16x4*)(Wb + m * 65536 + off + k * 4) = o;
        }
    }
}

// ---------------------------------------------------------------------------
// K1: fused GroupNorm-apply + QKV MFMA GEMM. grid (64 pixblk, 6: z*2+och).
// (unchanged; qs = QSCALE)
// ---------------------------------------------------------------------------
__global__ __launch_bounds__(256) void gn_qkv(
    const float* __restrict__ X, const float* __restrict__ gamma,
    const float* __restrict__ beta,
    const float* __restrict__ psum, const float* __restrict__ pssq,
    const __bf16* __restrict__ Wb,
    const float* __restrict__ bq, const float* __restrict__ bk,
    const float* __restrict__ bv,
    __bf16* __restrict__ Qb, __bf16* __restrict__ Kb, __bf16* __restrict__ Vb)
{
    __shared__ __bf16 tile[64 * XPITCH];
    __shared__ float al[256], bl[256];

    const int t = threadIdx.x, lane = t & 63, wave = t >> 6;
    const int l16 = lane & 15, quad = lane >> 4;
    const int p0 = blockIdx.x * 64;
    const int z = blockIdx.y >> 1, och = blockIdx.y & 1;

    {
        const int g = t >> 3;
        float s = 0.f, q = 0.f;
        #pragma unroll
        for (int j = 0; j < 8; ++j) { s += psum[g * 8 + j]; q += pssq[g * 8 + j]; }
        const float mu  = s * (1.f / GSIZE);
        const float var = q * (1.f / GSIZE) - mu * mu;
        const float a = gamma[t] * rsqrtf(var + 1e-6f);
        al[t] = a;
        bl[t] = beta[t] - mu * a;
    }
    __syncthreads();

    #pragma unroll 4
    for (int i = 0; i < 16; ++i) {
        const int c4 = wave * 64 + i * 4;
        f32x4 a4 = *(const f32x4*)(al + c4);
        f32x4 b4 = *(const f32x4*)(bl + c4);
        bf16x4 pk;
        pk[0] = (__bf16)(X[(c4 + 0) * NPIX + p0 + lane] * a4[0] + b4[0]);
        pk[1] = (__bf16)(X[(c4 + 1) * NPIX + p0 + lane] * a4[1] + b4[1]);
        pk[2] = (__bf16)(X[(c4 + 2) * NPIX + p0 + lane] * a4[2] + b4[2]);
        pk[3] = (__bf16)(X[(c4 + 3) * NPIX + p0 + lane] * a4[3] + b4[3]);
        *(bf16x4*)(tile + lane * XPITCH + c4) = pk;
    }
    __syncthreads();

    const int pw = wave * 16;
    bf16x8 xf[8];
    #pragma unroll
    for (int kc = 0; kc < 8; ++kc)
        xf[kc] = *(const bf16x8*)(tile + (pw + l16) * XPITCH + kc * 32 + quad * 8);

    const __bf16* Wz = Wb + z * 65536;
    const float* bias = (z == 0) ? bq : (z == 1) ? bk : bv;

    if (z < 2) {
        const float qs = (z == 0) ? QSCALE : 1.f;
        __bf16* dst = (z == 0) ? Qb : Kb;
        #pragma unroll
        for (int grp = 0; grp < 2; ++grp) {
            f32x4 acc[4] = {};
            #pragma unroll
            for (int kc = 0; kc < 8; ++kc) {
                #pragma unroll
                for (int u = 0; u < 4; ++u) {
                    bf16x8 wf = *(const bf16x8*)(Wz + (och * 128 + (grp * 4 + u) * 16 + l16) * CCH + kc * 32 + quad * 8);
                    acc[u] = __builtin_amdgcn_mfma_f32_16x16x32_bf16(wf, xf[kc], acc[u], 0, 0, 0);
                }
            }
            #pragma unroll
            for (int u = 0; u < 4; ++u) {
                const int ot = och * 8 + grp * 4 + u;
                f32x4 bz = *(const f32x4*)(bias + och * 128 + (grp * 4 + u) * 16 + quad * 4);
                bf16x4 o;
                o[0] = (__bf16)(acc[u][0] + bz[0] * qs);
                o[1] = (__bf16)(acc[u][1] + bz[1] * qs);
                o[2] = (__bf16)(acc[u][2] + bz[2] * qs);
                o[3] = (__bf16)(acc[u][3] + bz[3] * qs);
                const int head = ot >> 2, dloc = (ot & 3) * 16 + quad * 4;
                *(bf16x4*)(dst + head * (NPIX * HD) + (p0 + pw + l16) * HD + dloc) = o;
            }
        }
    } else {
        #pragma unroll
        for (int grp = 0; grp < 2; ++grp) {
            f32x4 acc[4] = {};
            #pragma unroll
            for (int kc = 0; kc < 8; ++kc) {
                #pragma unroll
                for (int u = 0; u < 4; ++u) {
                    bf16x8 wf = *(const bf16x8*)(Wz + (och * 128 + (grp * 4 + u) * 16 + l16) * CCH + kc * 32 + quad * 8);
                    acc[u] = __builtin_amdgcn_mfma_f32_16x16x32_bf16(xf[kc], wf, acc[u], 0, 0, 0);
                }
            }
            #pragma unroll
            for (int u = 0; u < 4; ++u) {
                const int oc = och * 128 + (grp * 4 + u) * 16 + l16;
                const float bz = bias[oc];
                bf16x4 o;
                o[0] = (__bf16)(acc[u][0] + bz); o[1] = (__bf16)(acc[u][1] + bz);
                o[2] = (__bf16)(acc[u][2] + bz); o[3] = (__bf16)(acc[u][3] + bz);
                *(bf16x4*)(Vb + oc * NPIX + p0 + pw + quad * 4) = o;
            }
        }
    }
}

// ---------------------------------------------------------------------------
// K2 (R21): R20 (512-thr, 8-wave, barrier-free, 2 waves/SIMD) + split K/V
// waits + T5 setprio. R20 post-mortem: win (attn ~27 us) but still ~3x the
// ~8-9 us issue floor; residual is stall/arbitration. Two fixes:
//  1. Split the single vmcnt(8) into vmcnt(12) [K(it) ready -> K-reads,
//     stageK(it+2), QK] then vmcnt(8) [V(it) ready -> V-reads, stageV(it+2),
//     PV]. Queue sim: steady-state K-wait is a no-op; V-wait drains exactly
//     V(it)+K(it+1); tail waits (4,0) at it==15. V gets an extra QK-phase to
//     arrive; staging issues earlier (m201's stage-before-MFMA pattern).
//  2. setprio(1) around MFMA clusters (T5): with 2 drifting waves/SIMD there
//     is genuine role diversity (m191 attn +4-7%; m190's null was lockstep).
// WAR on re-stage: ds_reads issued ~>=1 LDS-pipe latency before the DMA's
// L2 round-trip write lands (proven R17-R20).
// ---------------------------------------------------------------------------
#define OFFK0 0
#define OFFK1 32768
#define OFFV0 65536
#define OFFV1 98304
#define SMEMSZ 141312  // max(128K buffers, 139264 co + 2048 cl) via overlay

__global__ __launch_bounds__(512, 2) void attn_mfma(
    const __bf16* __restrict__ Qb, const __bf16* __restrict__ Kb,
    const __bf16* __restrict__ Vb, __bf16* __restrict__ Sb)
{
    __shared__ __align__(16) char smem[SMEMSZ];

    const int t = threadIdx.x, lane = t & 63, wave = t >> 6;   // wave 0..7
    const int l16 = lane & 15, quad = lane >> 4;

    const int bid  = blockIdx.x;
    const int head = (bid & 7) >> 1;                   // XCD-pair pinning
    const int qt   = ((bid >> 3) << 1) | (bid & 1);    // 0..63
    const int p0   = qt * 64;

    const __bf16* Qh = Qb + head * (NPIX * HD);

    // Q B-frags for 64 shared rows: B[k=d][n=row16]
    bf16x8 qf[4][2];
    #pragma unroll
    for (int rt = 0; rt < 4; ++rt) {
        const __bf16* qp = Qh + (p0 + rt * 16 + l16) * HD + quad * 8;
        qf[rt][0] = *(const bf16x8*)(qp);
        qf[rt][1] = *(const bf16x8*)(qp + 32);
    }

    bf16x8 ones;
    #pragma unroll
    for (int j = 0; j < 8; ++j) ones[j] = (__bf16)1.0f;

    f32x4 l_acc[4] = {};
    f32x4 o_acc[4][4] = {};   // [dt][rt]

    // ---- staging (8 DMA instr / wave / tile), fully wave-private ----
    // wave owns keys [wave*32, wave*32+32) of each 256-key tile
    const int lr3 = lane >> 3, lc3 = lane & 7;     // K: row-in-chunk, col-chunk
    const int kcol = ((lc3 ^ lr3) << 4);           // K pre-swizzled global col
    const int vrow = lane >> 2;                    // V: d-row within instr group
    const int vchk = (((lane & 3) ^ (lane >> 4)) << 4);  // V pre-swizzled chunk
    const char* Kg = (const char*)(Kb + (head * NPIX) * HD);
    const char* Vg = (const char*)(Vb + (head * HD) * NPIX);

    auto stageK = [&](int it, int b) {
        char* dst = smem + (b ? OFFK1 : OFFK0) + wave * 4096;   // wave's 32 rows
        const char* src = Kg + (it * 256 + wave * 32) * 128;    // 128 B / K-row
        #pragma unroll
        for (int i = 0; i < 4; ++i)
            gload_lds16(src + (i * 8 + lr3) * 128 + kcol, dst + i * 1024);
    };
    auto stageV = [&](int it, int b) {
        // wave-private: all 64 d-rows x wave's 32 keys (64 B/row)
        char* dst = smem + (b ? OFFV1 : OFFV0) + wave * 4096;
        const char* src = Vg + it * 512 + wave * 64;
        #pragma unroll
        for (int i = 0; i < 4; ++i)
            gload_lds16(src + (i * 16 + vrow) * (NPIX * 2) + vchk, dst + i * 1024);
    };

    // S^T = K Q^T : C(key_local = kt*16+quad*4+r, row = rt*16+l16)
    auto qk = [&](bf16x8 k0, bf16x8 k1, bf16x8 k2, bf16x8 k3,
                  f32x4 (&s0)[4], f32x4 (&s1)[4]) {
        __builtin_amdgcn_s_setprio(1);
        #pragma unroll
        for (int rt = 0; rt < 4; ++rt) {
            s0[rt] = f32x4{0.f, 0.f, 0.f, 0.f};
            s1[rt] = f32x4{0.f, 0.f, 0.f, 0.f};
            s0[rt] = __builtin_amdgcn_mfma_f32_16x16x32_bf16(k0, qf[rt][0], s0[rt], 0, 0, 0);
            s0[rt] = __builtin_amdgcn_mfma_f32_16x16x32_bf16(k1, qf[rt][1], s0[rt], 0, 0, 0);
            s1[rt] = __builtin_amdgcn_mfma_f32_16x16x32_bf16(k2, qf[rt][0], s1[rt], 0, 0, 0);
            s1[rt] = __builtin_amdgcn_mfma_f32_16x16x32_bf16(k3, qf[rt][1], s1[rt], 0, 0, 0);
        }
        __builtin_amdgcn_s_setprio(0);
    };

    auto pvx = [&](const f32x4 (&s0)[4], const f32x4 (&s1)[4],
                   bf16x8 v0, bf16x8 v1, bf16x8 v2, bf16x8 v3) {
        #pragma unroll
        for (int rt = 0; rt < 4; ++rt) {
            unsigned a0 = pack_bf16x2(EXP2(s0[rt][0]), EXP2(s0[rt][1]));
            unsigned a1 = pack_bf16x2(EXP2(s0[rt][2]), EXP2(s0[rt][3]));
            unsigned b0 = pack_bf16x2(EXP2(s1[rt][0]), EXP2(s1[rt][1]));
            unsigned b1 = pack_bf16x2(EXP2(s1[rt][2]), EXP2(s1[rt][3]));
            // swap32 then swap16: (a0,b0) -> (w0,w2); (a1,b1) -> (w1,w3)
            asm("v_permlane32_swap_b32 %0, %1" : "+v"(a0), "+v"(b0));
            asm("v_permlane32_swap_b32 %0, %1" : "+v"(a1), "+v"(b1));
            asm("v_permlane16_swap_b32 %0, %1" : "+v"(a0), "+v"(b0));
            asm("v_permlane16_swap_b32 %0, %1" : "+v"(a1), "+v"(b1));
            uint32x4 w;
            w[0] = a0; w[1] = a1; w[2] = b0; w[3] = b1;
            const bf16x8 bp = __builtin_bit_cast(bf16x8, w);  // B[k=key32][n=row]
            __builtin_amdgcn_s_setprio(1);
            l_acc[rt] = __builtin_amdgcn_mfma_f32_16x16x32_bf16(ones, bp, l_acc[rt], 0, 0, 0);
            o_acc[0][rt] = __builtin_amdgcn_mfma_f32_16x16x32_bf16(v0, bp, o_acc[0][rt], 0, 0, 0);
            o_acc[1][rt] = __builtin_amdgcn_mfma_f32_16x16x32_bf16(v1, bp, o_acc[1][rt], 0, 0, 0);
            o_acc[2][rt] = __builtin_amdgcn_mfma_f32_16x16x32_bf16(v2, bp, o_acc[2][rt], 0, 0, 0);
            o_acc[3][rt] = __builtin_amdgcn_mfma_f32_16x16x32_bf16(v3, bp, o_acc[3][rt], 0, 0, 0);
            __builtin_amdgcn_s_setprio(0);
        }
    };

    // prologue: tiles 0 and 1 in flight (16 DMAs / wave)
    stageK(0, 0); stageV(0, 0);
    stageK(1, 1); stageV(1, 1);

    const int ksw = ((l16 & 7) << 4);
    const int vsw = ((quad ^ (l16 >> 2)) << 4);

    #pragma unroll 1
    for (int it = 0; it < 16; ++it) {
        const int b = it & 1;

        // -- phase 1: K(it) ready -> K-reads, stage K(it+2), QK --
        if (it == 15) asm volatile("s_waitcnt vmcnt(4)" ::: "memory");
        else          asm volatile("s_waitcnt vmcnt(12)" ::: "memory");
        __builtin_amdgcn_sched_barrier(0);

        const char* bk = smem + (b ? OFFK1 : OFFK0) + wave * 4096;
        const int kr0 = l16 * 128;
        bf16x8 k0 = *(const bf16x8*)(bk + kr0 + ((quad * 16) ^ ksw));
        bf16x8 k1 = *(const bf16x8*)(bk + kr0 + ((64 + quad * 16) ^ ksw));
        bf16x8 k2 = *(const bf16x8*)(bk + kr0 + 2048 + ((quad * 16) ^ ksw));
        bf16x8 k3 = *(const bf16x8*)(bk + kr0 + 2048 + ((64 + quad * 16) ^ ksw));
        if (it < 14) stageK(it + 2, b);

        f32x4 s0[4], s1[4];
        qk(k0, k1, k2, k3, s0, s1);

        // -- phase 2: V(it) ready -> V-reads, stage V(it+2), PV --
        if (it == 15) asm volatile("s_waitcnt vmcnt(0)" ::: "memory");
        else          asm volatile("s_waitcnt vmcnt(8)" ::: "memory");
        __builtin_amdgcn_sched_barrier(0);

        const char* bv = smem + (b ? OFFV1 : OFFV0) + wave * 4096;
        bf16x8 v0 = *(const bf16x8*)(bv + (l16) * 64 + vsw);
        bf16x8 v1 = *(const bf16x8*)(bv + (16 + l16) * 64 + vsw);
        bf16x8 v2 = *(const bf16x8*)(bv + (32 + l16) * 64 + vsw);
        bf16x8 v3 = *(const bf16x8*)(bv + (48 + l16) * 64 + vsw);
        if (it < 14) stageV(it + 2, b);

        pvx(s0, s1, v0, v1, v2, v3);
    }

    // ---- in-LDS 8-way key merge (overlay over the K/V buffers) ----
    __syncthreads();   // waves drift in the barrier-free loop; align before overlay
    float* co = (float*)smem;                  // 8 x 64 x 68 f32 = 139264 B
    float* cl = (float*)(smem + 139264);       // 8 x 64 f32

    #pragma unroll
    for (int dt = 0; dt < 4; ++dt)
        #pragma unroll
        for (int rt = 0; rt < 4; ++rt)
            *(f32x4*)(co + wave * 4352 + (rt * 16 + l16) * 68 + dt * 16 + quad * 4) = o_acc[dt][rt];
    if (quad == 0) {
        #pragma unroll
        for (int rt = 0; rt < 4; ++rt)
            cl[wave * 64 + rt * 16 + l16] = l_acc[rt][0];
    }
    __syncthreads();

    {
        const int row = t >> 3, dc = (t & 7) * 8;   // 512 thr: 64 rows x 8 d each
        float l = 0.f;
        #pragma unroll
        for (int w = 0; w < 8; ++w) l += cl[w * 64 + row];
        const float inv = 1.f / l;
        f32x4 s0 = {0.f, 0.f, 0.f, 0.f}, s1 = {0.f, 0.f, 0.f, 0.f};
        #pragma unroll
        for (int w = 0; w < 8; ++w) {
            s0 += *(const f32x4*)(co + w * 4352 + row * 68 + dc);
            s1 += *(const f32x4*)(co + w * 4352 + row * 68 + dc + 4);
        }
        bf16x8 o;
        #pragma unroll
        for (int j = 0; j < 4; ++j) {
            o[j]     = (__bf16)(s0[j] * inv);
            o[j + 4] = (__bf16)(s1[j] * inv);
        }
        *(bf16x8*)(Sb + (p0 + row) * CCH + head * HD + dc) = o;
    }
}

// ---------------------------------------------------------------------------
// K3: proj bf16 MFMA GEMM + bias + residual, fp32 out [c][pix].
// (R12/R17-proven Sb-based version)
// ---------------------------------------------------------------------------
__global__ __launch_bounds__(256) void gemm_proj(
    const __bf16* __restrict__ Sb, const __bf16* __restrict__ Wpb,
    const float* __restrict__ bias, const float* __restrict__ X,
    float* __restrict__ Out)
{
    __shared__ __bf16 Bs[32 * XPITCH];

    const int t = threadIdx.x, lane = t & 63, wave = t >> 6;
    const int l16 = lane & 15, quad = lane >> 4;
    const int p0  = blockIdx.x * 32;
    const int och = blockIdx.y;

    #pragma unroll
    for (int pg = 0; pg < 4; ++pg) {
        bf16x8 v = *(const bf16x8*)(Sb + t * NPIX + p0 + pg * 8);
        #pragma unroll
        for (int j = 0; j < 8; ++j)
            Bs[(pg * 8 + j) * XPITCH + t] = v[j];
    }
    __syncthreads();

    const int pixset = wave & 1, ocset = wave >> 1;
    bf16x8 af[8];
    #pragma unroll
    for (int kc = 0; kc < 8; ++kc)
        af[kc] = *(const bf16x8*)(Bs + (pixset * 16 + l16) * XPITCH + kc * 32 + quad * 8);

    #pragma unroll
    for (int u = 0; u < 4; ++u) {
        f32x4 acc = {};
        const int oc_t = och * 128 + ocset * 64 + u * 16;
        #pragma unroll
        for (int kc = 0; kc < 8; ++kc) {
            bf16x8 wf = *(const bf16x8*)(Wpb + (oc_t + l16) * CCH + kc * 32 + quad * 8);
            acc = __builtin_amdgcn_mfma_f32_16x16x32_bf16(af[kc], wf, acc, 0, 0, 0);
        }
        const int oc  = oc_t + l16;
        const int pix = p0 + pixset * 16 + quad * 4;
        const float bz = bias[oc];
        f32x4 r4 = *(const f32x4*)(X + oc * NPIX + pix);
        f32x4 y;
        y[0] = acc[0] + bz + r4[0];
        y[1] = acc[1] + bz + r4[1];
        y[2] = acc[2] + bz + r4[2];
        y[3] = acc[3] + bz + r4[3];
        *(f32x4*)(Out + oc * NPIX + pix) = y;
    }
}

// ---------------------------------------------------------------------------
extern "C" void kernel_launch(void* const* d_in, const int* in_sizes, int n_in,
                              void* d_out, int out_size, void* d_ws, size_t ws_size,
                              hipStream_t stream)
{
    const float* x     = (const float*)d_in[0];
    const float* gamma = (const float*)d_in[1];
    const float* beta  = (const float*)d_in[2];
    const float* Wq    = (const float*)d_in[3];
    const float* bq    = (const float*)d_in[4];
    const float* Wk    = (const float*)d_in[5];
    const float* bk    = (const float*)d_in[6];
    const float* Wv    = (const float*)d_in[7];
    const float* bv    = (const float*)d_in[8];
    const float* Wp    = (const float*)d_in[9];
    const float* bp    = (const float*)d_in[10];
    float* out = (float*)d_out;

    char* ws = (char*)d_ws;
    float*  psum = (float*)(ws);                // 1KB stats partial sums
    float*  pssq = (float*)(ws + 1024);         // 1KB
    __bf16* Wb   = (__bf16*)(ws + 65536);       // 512KB bf16 4x[256][256]
    __bf16* Qb   = (__bf16*)(ws + (1 << 20));   // 2MB bf16 [head][pix][64]
    __bf16* Kb   = (__bf16*)(ws + (3 << 20));   // 2MB bf16 [head][pix][64]
    __bf16* Vb   = (__bf16*)(ws + (5 << 20));   // 2MB bf16 [c][pix]
    __bf16* Sb   = (__bf16*)(ws + (7 << 20));   // 2MB bf16 flat F

    stats_wconv<<<320, 256, 0, stream>>>(x, Wq, Wk, Wv, Wp, psum, pssq, Wb);

    dim3 gq(64, 6);
    gn_qkv<<<gq, 256, 0, stream>>>(x, gamma, beta, psum, pssq, Wb,
                                   bq, bk, bv, Qb, Kb, Vb);

    attn_mfma<<<256, 512, 0, stream>>>(Qb, Kb, Vb, Sb);

    dim3 gp(128, 2);
    gemm_proj<<<gp, 256, 0, stream>>>(Sb, Wb + 3 * 65536, bp, x, out);
}